// Round 2
// baseline (487.973 us; speedup 1.0000x reference)
//
#include <hip/hip_runtime.h>

#define BB 64
#define SS 4096
#define DD 64
#define FF 256
#define INVS 0.35355339059327373f   // 1/sqrt(8) = 64^-0.25
#define FSCALE 0.0625f              // 256^-0.5

// workspace layout (float-index offsets)
#define KV_OFF_F    0                          // [BB][FF][DD]
#define KSUM_OFF_F  (BB*FF*DD)                 // [BB][FF]
#define MKEY_OFF_F  (KSUM_OFF_F + BB*FF)       // [BB] uint keys (true max k_proj)
#define NKEY_OFF_F  (MKEY_OFF_F + BB)          // [BB] uint keys (max raw row |k|^2)
#define MSUM_OFF_F  (NKEY_OFF_F + BB)          // [BB][DD] column sums of raw k
#define WS_ZERO_F   (MSUM_OFF_F + BB*DD)
#define WS_ZERO_BYTES (WS_ZERO_F * 4)

typedef _Float16 f16;
typedef __attribute__((ext_vector_type(4))) _Float16 f16x4;
typedef __attribute__((ext_vector_type(8))) _Float16 f16x8;
typedef __attribute__((ext_vector_type(4))) float f32x4;

__device__ __forceinline__ unsigned fkey(float f) {
    unsigned b = __float_as_uint(f);
    return (f < 0.0f) ? ~b : (b | 0x80000000u);
}
__device__ __forceinline__ float funkey(unsigned k) {
    return (k & 0x80000000u) ? __uint_as_float(k ^ 0x80000000u) : __uint_as_float(~k);
}
__device__ __forceinline__ void splitf(float x, f16& h, f16& l) {
    h = (f16)x;
    l = (f16)(x - (float)h);
}

// ---------------------------------------------------------------------------
// K1: per-b column sums of raw k (mean) + max raw row-norm^2. (unchanged)
// ---------------------------------------------------------------------------
__global__ __launch_bounds__(256) void k_stats(const float* __restrict__ kin,
                                               float* __restrict__ msum,
                                               unsigned* __restrict__ nkey) {
    const int b = blockIdx.y, chunk = blockIdx.x;
    const int t = threadIdx.x, row = t >> 4, c16 = t & 15;
    const float4* kg = (const float4*)(kin + (size_t)b * (SS * DD));
    float4 cacc = make_float4(0.f, 0.f, 0.f, 0.f);
    float nmax = 0.f;
    const int s0 = chunk * 256;
    #pragma unroll 4
    for (int it = 0; it < 16; ++it) {
        const int s = s0 + it * 16 + row;
        float4 x = kg[s * 16 + c16];
        cacc.x += x.x; cacc.y += x.y; cacc.z += x.z; cacc.w += x.w;
        float sq = x.x * x.x + x.y * x.y + x.z * x.z + x.w * x.w;
        #pragma unroll
        for (int off = 1; off <= 8; off <<= 1) sq += __shfl_xor(sq, off);
        nmax = fmaxf(nmax, sq);
    }
    __shared__ float csum[64];
    __shared__ float wm[4];
    if (t < 64) csum[t] = 0.f;
    __syncthreads();
    atomicAdd(&csum[c16 * 4 + 0], cacc.x);
    atomicAdd(&csum[c16 * 4 + 1], cacc.y);
    atomicAdd(&csum[c16 * 4 + 2], cacc.z);
    atomicAdd(&csum[c16 * 4 + 3], cacc.w);
    nmax = fmaxf(nmax, __shfl_xor(nmax, 16));
    nmax = fmaxf(nmax, __shfl_xor(nmax, 32));
    if ((t & 63) == 0) wm[t >> 6] = nmax;
    __syncthreads();
    if (t < 64) atomicAdd(&msum[b * DD + t], csum[t]);
    if (t == 0) {
        float mx = fmaxf(fmaxf(wm[0], wm[1]), fmaxf(wm[2], wm[3]));
        atomicMax(&nkey[b], fkey(mx));
    }
}

// ---------------------------------------------------------------------------
// K2 (MFMA): phi_k^T V.
// Round-2 changes: grid (8,64) -> 2 blocks/CU (occupancy 22->~44%);
// XOR granule swizzle on pT/vT: element (x,s) at x*40 + ((s>>3)^((x>>2)&3))*8
// + (s&7) -- kills the 16-way vT write conflict, reads stay b128;
// ksum accumulated in registers (no LDS atomics).
// ---------------------------------------------------------------------------
__global__ __launch_bounds__(512, 4) void k_kv(const float* __restrict__ kin,
                                               const float* __restrict__ vin,
                                               const float* __restrict__ w,
                                               float* __restrict__ ws) {
    float* kv = ws + KV_OFF_F;
    float* ksum = ws + KSUM_OFF_F;
    unsigned* mkey = (unsigned*)ws + MKEY_OFF_F;
    const unsigned* nkey = (const unsigned*)ws + NKEY_OFF_F;
    const float* msum = ws + MSUM_OFF_F;

    const int b = blockIdx.y, chunk = blockIdx.x;
    const int t = threadIdx.x;
    const int wid = t >> 6, l = t & 63, quad = l >> 4, m = l & 15;
    const int st = wid & 1, fgroup = wid >> 1;   // phase-A tile mapping

    __shared__ __align__(16) f16 kH[32 * 72], kL[32 * 72];
    __shared__ __align__(16) f16 vTH[64 * 40], vTL[64 * 40];
    __shared__ __align__(16) f16 pTH[256 * 40], pTL[256 * 40];
    __shared__ __align__(16) float cS[32];
    __shared__ __align__(16) float muL[64];
    __shared__ float redw[8];
    __shared__ float mhatL;

    if (t < 64) {
        float mv = msum[b * DD + t] * (1.0f / 4096.0f);
        muL[t] = mv;
        float sq = mv * mv;
        #pragma unroll
        for (int off = 32; off; off >>= 1) sq += __shfl_xor(sq, off);
        if (t == 0) mhatL = (sqrtf(funkey(nkey[b])) + sqrtf(sq)) * INVS;
    }

    f16x8 wbH[4][2], wbL[4][2];
    #pragma unroll
    for (int ff = 0; ff < 4; ++ff) {
        #pragma unroll
        for (int ks = 0; ks < 2; ++ks) {
            const float* wp = w + (((fgroup * 4 + ff) * 16 + m) * 64 + ks * 32 + quad * 8);
            float4 x0 = *(const float4*)wp;
            float4 x1 = *(const float4*)(wp + 4);
            f16 h, lo;
            splitf(x0.x, h, lo); wbH[ff][ks][0] = h; wbL[ff][ks][0] = lo;
            splitf(x0.y, h, lo); wbH[ff][ks][1] = h; wbL[ff][ks][1] = lo;
            splitf(x0.z, h, lo); wbH[ff][ks][2] = h; wbL[ff][ks][2] = lo;
            splitf(x0.w, h, lo); wbH[ff][ks][3] = h; wbL[ff][ks][3] = lo;
            splitf(x1.x, h, lo); wbH[ff][ks][4] = h; wbL[ff][ks][4] = lo;
            splitf(x1.y, h, lo); wbH[ff][ks][5] = h; wbL[ff][ks][5] = lo;
            splitf(x1.z, h, lo); wbH[ff][ks][6] = h; wbL[ff][ks][6] = lo;
            splitf(x1.w, h, lo); wbH[ff][ks][7] = h; wbL[ff][ks][7] = lo;
        }
    }
    __syncthreads();
    const float mhat = mhatL;
    const int srow = t >> 4, scol = t & 15;
    const float4 mu4 = *(const float4*)&muL[scol * 4];

    f32x4 acc2[8];
    #pragma unroll
    for (int i = 0; i < 8; ++i) acc2[i] = (f32x4){0.f, 0.f, 0.f, 0.f};
    float ksacc[4] = {0.f, 0.f, 0.f, 0.f};
    float dmax = -1e30f;

    const int rbase = chunk * 512;
    const float4* kg = (const float4*)(kin + (size_t)b * (SS * DD));
    const float4* vg = (const float4*)(vin + (size_t)b * (SS * DD));

    float4 k4 = kg[(rbase + srow) * 16 + scol];
    float4 v4 = vg[(rbase + srow) * 16 + scol];

    // staging-side swizzle constants
    const int vgW = scol & 3;            // (d>>2)&3 for d = scol*4+u
    const int sG = srow >> 3, sIn = srow & 7;

    for (int it = 0; it < 16; ++it) {
        float4 kc;
        kc.x = (k4.x - mu4.x) * INVS; kc.y = (k4.y - mu4.y) * INVS;
        kc.z = (k4.z - mu4.z) * INVS; kc.w = (k4.w - mu4.w) * INVS;
        float sq = kc.x * kc.x + kc.y * kc.y + kc.z * kc.z + kc.w * kc.w;
        #pragma unroll
        for (int off = 1; off <= 8; off <<= 1) sq += __shfl_xor(sq, off);
        if (scol == 0) cS[srow] = 0.5f * sq;
        {
            f16x4 khv, klv;
            f16 h, lo;
            splitf(kc.x, h, lo); khv[0] = h; klv[0] = lo;
            splitf(kc.y, h, lo); khv[1] = h; klv[1] = lo;
            splitf(kc.z, h, lo); khv[2] = h; klv[2] = lo;
            splitf(kc.w, h, lo); khv[3] = h; klv[3] = lo;
            *(f16x4*)&kH[srow * 72 + scol * 4] = khv;
            *(f16x4*)&kL[srow * 72 + scol * 4] = klv;
        }
        #pragma unroll
        for (int u = 0; u < 4; ++u) {
            float vv = (&v4.x)[u];
            f16 vh, vl;
            splitf(vv, vh, vl);
            const int idx = (scol * 4 + u) * 40 + ((sG ^ vgW) << 3) + sIn;
            vTH[idx] = vh;
            vTL[idx] = vl;
        }
        __syncthreads();

        f16x8 aH[2], aL[2];
        #pragma unroll
        for (int ks = 0; ks < 2; ++ks) {
            aH[ks] = *(const f16x8*)&kH[(st * 16 + m) * 72 + ks * 32 + quad * 8];
            aL[ks] = *(const f16x8*)&kL[(st * 16 + m) * 72 + ks * 32 + quad * 8];
        }
        const float4 c4 = *(const float4*)&cS[st * 16 + quad * 4];
        const int mG = (m >> 2) & 3;                     // (f>>2)&3 and (d>>2)&3 for lane m
        const int pG = ((st * 2 + (quad >> 1)) ^ mG);    // swizzled s-granule for pT write
        const int pOff = (pG << 3) + ((quad & 1) << 2);
        #pragma unroll
        for (int ff = 0; ff < 4; ++ff) {
            f32x4 acc = (f32x4){0.f, 0.f, 0.f, 0.f};
            #pragma unroll
            for (int ks = 0; ks < 2; ++ks) {
                acc = __builtin_amdgcn_mfma_f32_16x16x32_f16(aH[ks], wbH[ff][ks], acc, 0, 0, 0);
                acc = __builtin_amdgcn_mfma_f32_16x16x32_f16(aH[ks], wbL[ff][ks], acc, 0, 0, 0);
                acc = __builtin_amdgcn_mfma_f32_16x16x32_f16(aL[ks], wbH[ff][ks], acc, 0, 0, 0);
            }
            float ksp = 0.f;
            f16x4 phv, plv;
            #pragma unroll
            for (int r = 0; r < 4; ++r) {
                float d = acc[r];
                dmax = fmaxf(dmax, d);
                float p = __expf(d - (&c4.x)[r] - mhat) * FSCALE;
                ksp += p;
                f16 h, lo;
                splitf(p, h, lo);
                phv[r] = h; plv[r] = lo;
            }
            const int f = (fgroup * 4 + ff) * 16 + m;
            *(f16x4*)&pTH[f * 40 + pOff] = phv;
            *(f16x4*)&pTL[f * 40 + pOff] = plv;
            ksp += __shfl_xor(ksp, 16);
            ksp += __shfl_xor(ksp, 32);
            ksacc[ff] += ksp;
        }
        __syncthreads();

        if (it < 15) {
            k4 = kg[(rbase + (it + 1) * 32 + srow) * 16 + scol];
            v4 = vg[(rbase + (it + 1) * 32 + srow) * 16 + scol];
        }

        f16x8 aH2[2], aL2[2], bH2[4], bL2[4];
        #pragma unroll
        for (int tt = 0; tt < 2; ++tt) {
            const int f = (wid * 2 + tt) * 16 + m;
            const int off = f * 40 + ((quad ^ mG) << 3);
            aH2[tt] = *(const f16x8*)&pTH[off];
            aL2[tt] = *(const f16x8*)&pTL[off];
        }
        #pragma unroll
        for (int dtile = 0; dtile < 4; ++dtile) {
            const int d = dtile * 16 + m;
            const int off = d * 40 + ((quad ^ mG) << 3);
            bH2[dtile] = *(const f16x8*)&vTH[off];
            bL2[dtile] = *(const f16x8*)&vTL[off];
        }
        #pragma unroll
        for (int tt = 0; tt < 2; ++tt) {
            #pragma unroll
            for (int dtile = 0; dtile < 4; ++dtile) {
                f32x4 a = acc2[tt * 4 + dtile];
                a = __builtin_amdgcn_mfma_f32_16x16x32_f16(aH2[tt], bH2[dtile], a, 0, 0, 0);
                a = __builtin_amdgcn_mfma_f32_16x16x32_f16(aH2[tt], bL2[dtile], a, 0, 0, 0);
                a = __builtin_amdgcn_mfma_f32_16x16x32_f16(aL2[tt], bH2[dtile], a, 0, 0, 0);
                acc2[tt * 4 + dtile] = a;
            }
        }
        __syncthreads();
    }

    #pragma unroll
    for (int tt = 0; tt < 2; ++tt) {
        #pragma unroll
        for (int dtile = 0; dtile < 4; ++dtile) {
            #pragma unroll
            for (int r = 0; r < 4; ++r) {
                const int f = (wid * 2 + tt) * 16 + quad * 4 + r;
                const int d = dtile * 16 + m;
                atomicAdd(&kv[((size_t)b * FF + f) * DD + d], acc2[tt * 4 + dtile][r]);
            }
        }
    }
    if (l < 16) {
        #pragma unroll
        for (int ff = 0; ff < 4; ++ff)
            atomicAdd(&ksum[b * FF + (fgroup * 4 + ff) * 16 + l], ksacc[ff]);
    }
    #pragma unroll
    for (int off = 32; off; off >>= 1) dmax = fmaxf(dmax, __shfl_xor(dmax, off));
    if (l == 0) redw[wid] = dmax;
    __syncthreads();
    if (t == 0) {
        float mx = redw[0];
        #pragma unroll
        for (int i = 1; i < 8; ++i) mx = fmaxf(mx, redw[i]);
        atomicMax(&mkey[b], fkey(mx));
    }
}

// ---------------------------------------------------------------------------
// K3 (MFMA): out = phi_q . kv / deno. (unchanged from round 1 — proven)
// ---------------------------------------------------------------------------
__global__ __launch_bounds__(512, 2) void k_out(const float* __restrict__ qin,
                                                const float* __restrict__ w,
                                                const float* __restrict__ ws,
                                                float* __restrict__ outp) {
    const float* kv = ws + KV_OFF_F;
    const float* ksum = ws + KSUM_OFF_F;
    const unsigned* mkey = (const unsigned*)ws + MKEY_OFF_F;
    const unsigned* nkey = (const unsigned*)ws + NKEY_OFF_F;
    const float* msum = ws + MSUM_OFF_F;

    const int b = blockIdx.y, chunk = blockIdx.x, t = threadIdx.x;
    const int wid = t >> 6, l = t & 63, quad = l >> 4, m = l & 15;
    const int st = wid & 1, fgroup = wid >> 1;   // phase A: (s-tile, f-group)
    const int dt = wid >> 1;                     // phase B: (s-tile=st, d-tile)

    __shared__ __align__(16) f16 qH[32 * 72], qL[32 * 72];
    __shared__ __align__(16) f16 pH[32 * 264], pL[32 * 264];
    __shared__ __align__(16) float oL[32 * 68];
    __shared__ float cS[32], mqL[32];
    __shared__ float ksL[256];
    __shared__ float denoP[4][32], dmaxP[4][32];
    __shared__ float scaleL[32];
    __shared__ float abL;

    if (t < 64) {
        float mv = msum[b * DD + t] * (1.0f / 4096.0f);
        float sq = mv * mv;
        #pragma unroll
        for (int off = 32; off; off >>= 1) sq += __shfl_xor(sq, off);
        if (t == 0) {
            float mhat = (sqrtf(funkey(nkey[b])) + sqrtf(sq)) * INVS;  // same ops as k_kv
            abL = __expf(mhat - funkey(mkey[b]));                      // alpha_b >= 1
        }
    }
    if (t < 256) ksL[t] = ksum[b * FF + t];

    f16x8 wbH[4][2], wbL[4][2];
    #pragma unroll
    for (int ff = 0; ff < 4; ++ff) {
        #pragma unroll
        for (int ks = 0; ks < 2; ++ks) {
            const float* wp = w + (((fgroup * 4 + ff) * 16 + m) * 64 + ks * 32 + quad * 8);
            float4 x0 = *(const float4*)wp;
            float4 x1 = *(const float4*)(wp + 4);
            f16 h, lo;
            splitf(x0.x, h, lo); wbH[ff][ks][0] = h; wbL[ff][ks][0] = lo;
            splitf(x0.y, h, lo); wbH[ff][ks][1] = h; wbL[ff][ks][1] = lo;
            splitf(x0.z, h, lo); wbH[ff][ks][2] = h; wbL[ff][ks][2] = lo;
            splitf(x0.w, h, lo); wbH[ff][ks][3] = h; wbL[ff][ks][3] = lo;
            splitf(x1.x, h, lo); wbH[ff][ks][4] = h; wbL[ff][ks][4] = lo;
            splitf(x1.y, h, lo); wbH[ff][ks][5] = h; wbL[ff][ks][5] = lo;
            splitf(x1.z, h, lo); wbH[ff][ks][6] = h; wbL[ff][ks][6] = lo;
            splitf(x1.w, h, lo); wbH[ff][ks][7] = h; wbL[ff][ks][7] = lo;
        }
    }

    f16x8 kvH[8], kvL[8];
    {
        const float* kvg = kv + (size_t)b * (FF * DD) + dt * 16 + m;
        #pragma unroll
        for (int ks = 0; ks < 8; ++ks) {
            #pragma unroll
            for (int j = 0; j < 8; ++j) {
                float x = kvg[(ks * 32 + quad * 8 + j) * 64];
                f16 h, lo;
                splitf(x, h, lo);
                kvH[ks][j] = h; kvL[ks][j] = lo;
            }
        }
    }
    __syncthreads();

    const int srow = t >> 4, scol = t & 15;
    const int rbase = chunk * 512;
    const float4* qg = (const float4*)qin + (size_t)b * (SS * 16);
    float4* og = (float4*)outp + (size_t)b * (SS * 16);

    float4 q4 = qg[(rbase + srow) * 16 + scol];

    for (int it = 0; it < 16; ++it) {
        float4 qs;
        qs.x = q4.x * INVS; qs.y = q4.y * INVS;
        qs.z = q4.z * INVS; qs.w = q4.w * INVS;
        float sq = qs.x * qs.x + qs.y * qs.y + qs.z * qs.z + qs.w * qs.w;
        #pragma unroll
        for (int off = 1; off <= 8; off <<= 1) sq += __shfl_xor(sq, off);
        if (scol == 0) { cS[srow] = 0.5f * sq; mqL[srow] = sqrtf(sq); }
        {
            f16x4 hv, lv;
            f16 h, lo;
            splitf(qs.x, h, lo); hv[0] = h; lv[0] = lo;
            splitf(qs.y, h, lo); hv[1] = h; lv[1] = lo;
            splitf(qs.z, h, lo); hv[2] = h; lv[2] = lo;
            splitf(qs.w, h, lo); hv[3] = h; lv[3] = lo;
            *(f16x4*)&qH[srow * 72 + scol * 4] = hv;
            *(f16x4*)&qL[srow * 72 + scol * 4] = lv;
        }
        __syncthreads();

        f16x8 bqH[2], bqL[2];
        #pragma unroll
        for (int ks = 0; ks < 2; ++ks) {
            bqH[ks] = *(const f16x8*)&qH[(st * 16 + m) * 72 + ks * 32 + quad * 8];
            bqL[ks] = *(const f16x8*)&qL[(st * 16 + m) * 72 + ks * 32 + quad * 8];
        }
        const float cs = cS[st * 16 + m];
        const float mq = mqL[st * 16 + m];
        float dpart = 0.f, dmax = -1e30f;
        #pragma unroll
        for (int ff = 0; ff < 4; ++ff) {
            f32x4 acc = (f32x4){0.f, 0.f, 0.f, 0.f};
            #pragma unroll
            for (int ks = 0; ks < 2; ++ks) {
                acc = __builtin_amdgcn_mfma_f32_16x16x32_f16(wbH[ff][ks], bqH[ks], acc, 0, 0, 0);
                acc = __builtin_amdgcn_mfma_f32_16x16x32_f16(wbH[ff][ks], bqL[ks], acc, 0, 0, 0);
                acc = __builtin_amdgcn_mfma_f32_16x16x32_f16(wbL[ff][ks], bqH[ks], acc, 0, 0, 0);
            }
            const int f0 = (fgroup * 4 + ff) * 16 + quad * 4;
            const float4 ksv = *(const float4*)&ksL[f0];
            f16x4 phv, plv;
            #pragma unroll
            for (int r = 0; r < 4; ++r) {
                float d = acc[r];
                dmax = fmaxf(dmax, d);
                float p = __expf(d - cs - mq);      // FSCALE folded into A later
                dpart = fmaf(p, (&ksv.x)[r], dpart);
                f16 h, lo;
                splitf(p, h, lo);
                phv[r] = h; plv[r] = lo;
            }
            *(f16x4*)&pH[(st * 16 + m) * 264 + f0] = phv;
            *(f16x4*)&pL[(st * 16 + m) * 264 + f0] = plv;
        }
        dpart += __shfl_xor(dpart, 16);
        dpart += __shfl_xor(dpart, 32);
        dmax = fmaxf(dmax, __shfl_xor(dmax, 16));
        dmax = fmaxf(dmax, __shfl_xor(dmax, 32));
        if (l < 16) {
            denoP[fgroup][st * 16 + l] = dpart;
            dmaxP[fgroup][st * 16 + l] = dmax;
        }
        __syncthreads();

        if (t < 32) {
            float dn0 = denoP[0][t] + denoP[1][t] + denoP[2][t] + denoP[3][t];
            float mt = fmaxf(fmaxf(dmaxP[0][t], dmaxP[1][t]),
                             fmaxf(dmaxP[2][t], dmaxP[3][t]));
            float A = abL * __expf(mqL[t] - mt) * FSCALE;
            float dn = fmaxf(A * dn0, 1e-4f);
            scaleL[t] = A / dn;
        }
        if (it < 15) q4 = qg[(rbase + (it + 1) * 32 + srow) * 16 + scol];

        f32x4 acc2 = (f32x4){0.f, 0.f, 0.f, 0.f};
        #pragma unroll
        for (int ks = 0; ks < 8; ++ks) {
            f16x8 paH = *(const f16x8*)&pH[(st * 16 + m) * 264 + ks * 32 + quad * 8];
            f16x8 paL = *(const f16x8*)&pL[(st * 16 + m) * 264 + ks * 32 + quad * 8];
            acc2 = __builtin_amdgcn_mfma_f32_16x16x32_f16(paH, kvH[ks], acc2, 0, 0, 0);
            acc2 = __builtin_amdgcn_mfma_f32_16x16x32_f16(paH, kvL[ks], acc2, 0, 0, 0);
            acc2 = __builtin_amdgcn_mfma_f32_16x16x32_f16(paL, kvH[ks], acc2, 0, 0, 0);
        }
        #pragma unroll
        for (int r = 0; r < 4; ++r)
            oL[(st * 16 + quad * 4 + r) * 68 + dt * 16 + m] = acc2[r];
        __syncthreads();

        {
            float4 ov = *(const float4*)&oL[srow * 68 + scol * 4];
            float s = scaleL[srow];
            og[(rbase + it * 32 + srow) * 16 + scol] =
                make_float4(ov.x * s, ov.y * s, ov.z * s, ov.w * s);
        }
    }
}

extern "C" void kernel_launch(void* const* d_in, const int* in_sizes, int n_in,
                              void* d_out, int out_size, void* d_ws, size_t ws_size,
                              hipStream_t stream) {
    (void)in_sizes; (void)n_in; (void)out_size; (void)ws_size;
    const float* q = (const float*)d_in[0];
    const float* k = (const float*)d_in[1];
    const float* v = (const float*)d_in[2];
    const float* w = (const float*)d_in[3];
    float* out = (float*)d_out;
    float* ws = (float*)d_ws;

    hipMemsetAsync(d_ws, 0, WS_ZERO_BYTES, stream);
    k_stats<<<dim3(16, 64), 256, 0, stream>>>(k, ws + MSUM_OFF_F, (unsigned*)ws + NKEY_OFF_F);
    k_kv<<<dim3(8, 64), 512, 0, stream>>>(k, v, w, ws);
    k_out<<<dim3(8, 64), 512, 0, stream>>>(q, w, ws, out);
}

// Round 3
// 379.264 us; speedup vs baseline: 1.2866x; 1.2866x over previous
//
#include <hip/hip_runtime.h>

#define BB 64
#define SS 4096
#define DD 64
#define FF 256
#define INVS 0.35355339059327373f   // 1/sqrt(8) = 64^-0.25
#define FSCALE 0.0625f              // 256^-0.5

// workspace layout (float-index offsets)
#define KV_OFF_F    0                          // [BB][FF][DD]
#define KSUM_OFF_F  (BB*FF*DD)                 // [BB][FF]
#define MKEY_OFF_F  (KSUM_OFF_F + BB*FF)       // [BB] uint keys (true max k_proj)
#define NKEY_OFF_F  (MKEY_OFF_F + BB)          // [BB] uint keys (max raw row |k|^2)
#define MSUM_OFF_F  (NKEY_OFF_F + BB)          // [BB][DD] column sums of raw k
#define WS_ZERO_F   (MSUM_OFF_F + BB*DD)
#define WS_ZERO_BYTES (WS_ZERO_F * 4)

typedef _Float16 f16;
typedef __attribute__((ext_vector_type(4))) _Float16 f16x4;
typedef __attribute__((ext_vector_type(8))) _Float16 f16x8;
typedef __attribute__((ext_vector_type(4))) float f32x4;

__device__ __forceinline__ unsigned fkey(float f) {
    unsigned b = __float_as_uint(f);
    return (f < 0.0f) ? ~b : (b | 0x80000000u);
}
__device__ __forceinline__ float funkey(unsigned k) {
    return (k & 0x80000000u) ? __uint_as_float(k ^ 0x80000000u) : __uint_as_float(~k);
}
__device__ __forceinline__ void splitf(float x, f16& h, f16& l) {
    h = (f16)x;
    l = (f16)(x - (float)h);
}

// ---------------------------------------------------------------------------
// K1: per-b column sums of raw k (mean) + max raw row-norm^2. (unchanged)
// ---------------------------------------------------------------------------
__global__ __launch_bounds__(256) void k_stats(const float* __restrict__ kin,
                                               float* __restrict__ msum,
                                               unsigned* __restrict__ nkey) {
    const int b = blockIdx.y, chunk = blockIdx.x;
    const int t = threadIdx.x, row = t >> 4, c16 = t & 15;
    const float4* kg = (const float4*)(kin + (size_t)b * (SS * DD));
    float4 cacc = make_float4(0.f, 0.f, 0.f, 0.f);
    float nmax = 0.f;
    const int s0 = chunk * 256;
    #pragma unroll 4
    for (int it = 0; it < 16; ++it) {
        const int s = s0 + it * 16 + row;
        float4 x = kg[s * 16 + c16];
        cacc.x += x.x; cacc.y += x.y; cacc.z += x.z; cacc.w += x.w;
        float sq = x.x * x.x + x.y * x.y + x.z * x.z + x.w * x.w;
        #pragma unroll
        for (int off = 1; off <= 8; off <<= 1) sq += __shfl_xor(sq, off);
        nmax = fmaxf(nmax, sq);
    }
    __shared__ float csum[64];
    __shared__ float wm[4];
    if (t < 64) csum[t] = 0.f;
    __syncthreads();
    atomicAdd(&csum[c16 * 4 + 0], cacc.x);
    atomicAdd(&csum[c16 * 4 + 1], cacc.y);
    atomicAdd(&csum[c16 * 4 + 2], cacc.z);
    atomicAdd(&csum[c16 * 4 + 3], cacc.w);
    nmax = fmaxf(nmax, __shfl_xor(nmax, 16));
    nmax = fmaxf(nmax, __shfl_xor(nmax, 32));
    if ((t & 63) == 0) wm[t >> 6] = nmax;
    __syncthreads();
    if (t < 64) atomicAdd(&msum[b * DD + t], csum[t]);
    if (t == 0) {
        float mx = fmaxf(fmaxf(wm[0], wm[1]), fmaxf(wm[2], wm[3]));
        atomicMax(&nkey[b], fkey(mx));
    }
}

// ---------------------------------------------------------------------------
// K2 (MFMA): phi_k^T V.
// Round-3: grid (8,64) for 2 blocks/CU, but launch_bounds back to (512,1) —
// the (512,4) hint forced a 64-VGPR cap and spilled ~500 MB to scratch
// (round-2 FETCH 586 MB). At ~104 VGPR + 61 KB LDS, 2 blocks/CU still fit.
// Keeps: XOR granule swizzle on pT/vT, register ksum accumulation.
// ---------------------------------------------------------------------------
__global__ __launch_bounds__(512, 1) void k_kv(const float* __restrict__ kin,
                                               const float* __restrict__ vin,
                                               const float* __restrict__ w,
                                               float* __restrict__ ws) {
    float* kv = ws + KV_OFF_F;
    float* ksum = ws + KSUM_OFF_F;
    unsigned* mkey = (unsigned*)ws + MKEY_OFF_F;
    const unsigned* nkey = (const unsigned*)ws + NKEY_OFF_F;
    const float* msum = ws + MSUM_OFF_F;

    const int b = blockIdx.y, chunk = blockIdx.x;
    const int t = threadIdx.x;
    const int wid = t >> 6, l = t & 63, quad = l >> 4, m = l & 15;
    const int st = wid & 1, fgroup = wid >> 1;   // phase-A tile mapping

    __shared__ __align__(16) f16 kH[32 * 72], kL[32 * 72];
    __shared__ __align__(16) f16 vTH[64 * 40], vTL[64 * 40];
    __shared__ __align__(16) f16 pTH[256 * 40], pTL[256 * 40];
    __shared__ __align__(16) float cS[32];
    __shared__ __align__(16) float muL[64];
    __shared__ float redw[8];
    __shared__ float mhatL;

    if (t < 64) {
        float mv = msum[b * DD + t] * (1.0f / 4096.0f);
        muL[t] = mv;
        float sq = mv * mv;
        #pragma unroll
        for (int off = 32; off; off >>= 1) sq += __shfl_xor(sq, off);
        if (t == 0) mhatL = (sqrtf(funkey(nkey[b])) + sqrtf(sq)) * INVS;
    }

    f16x8 wbH[4][2], wbL[4][2];
    #pragma unroll
    for (int ff = 0; ff < 4; ++ff) {
        #pragma unroll
        for (int ks = 0; ks < 2; ++ks) {
            const float* wp = w + (((fgroup * 4 + ff) * 16 + m) * 64 + ks * 32 + quad * 8);
            float4 x0 = *(const float4*)wp;
            float4 x1 = *(const float4*)(wp + 4);
            f16 h, lo;
            splitf(x0.x, h, lo); wbH[ff][ks][0] = h; wbL[ff][ks][0] = lo;
            splitf(x0.y, h, lo); wbH[ff][ks][1] = h; wbL[ff][ks][1] = lo;
            splitf(x0.z, h, lo); wbH[ff][ks][2] = h; wbL[ff][ks][2] = lo;
            splitf(x0.w, h, lo); wbH[ff][ks][3] = h; wbL[ff][ks][3] = lo;
            splitf(x1.x, h, lo); wbH[ff][ks][4] = h; wbL[ff][ks][4] = lo;
            splitf(x1.y, h, lo); wbH[ff][ks][5] = h; wbL[ff][ks][5] = lo;
            splitf(x1.z, h, lo); wbH[ff][ks][6] = h; wbL[ff][ks][6] = lo;
            splitf(x1.w, h, lo); wbH[ff][ks][7] = h; wbL[ff][ks][7] = lo;
        }
    }
    __syncthreads();
    const float mhat = mhatL;
    const int srow = t >> 4, scol = t & 15;
    const float4 mu4 = *(const float4*)&muL[scol * 4];

    f32x4 acc2[8];
    #pragma unroll
    for (int i = 0; i < 8; ++i) acc2[i] = (f32x4){0.f, 0.f, 0.f, 0.f};
    float ksacc[4] = {0.f, 0.f, 0.f, 0.f};
    float dmax = -1e30f;

    const int rbase = chunk * 512;
    const float4* kg = (const float4*)(kin + (size_t)b * (SS * DD));
    const float4* vg = (const float4*)(vin + (size_t)b * (SS * DD));

    float4 k4 = kg[(rbase + srow) * 16 + scol];
    float4 v4 = vg[(rbase + srow) * 16 + scol];

    // staging-side swizzle constants
    const int vgW = scol & 3;            // (d>>2)&3 for d = scol*4+u
    const int sG = srow >> 3, sIn = srow & 7;

    for (int it = 0; it < 16; ++it) {
        float4 kc;
        kc.x = (k4.x - mu4.x) * INVS; kc.y = (k4.y - mu4.y) * INVS;
        kc.z = (k4.z - mu4.z) * INVS; kc.w = (k4.w - mu4.w) * INVS;
        float sq = kc.x * kc.x + kc.y * kc.y + kc.z * kc.z + kc.w * kc.w;
        #pragma unroll
        for (int off = 1; off <= 8; off <<= 1) sq += __shfl_xor(sq, off);
        if (scol == 0) cS[srow] = 0.5f * sq;
        {
            f16x4 khv, klv;
            f16 h, lo;
            splitf(kc.x, h, lo); khv[0] = h; klv[0] = lo;
            splitf(kc.y, h, lo); khv[1] = h; klv[1] = lo;
            splitf(kc.z, h, lo); khv[2] = h; klv[2] = lo;
            splitf(kc.w, h, lo); khv[3] = h; klv[3] = lo;
            *(f16x4*)&kH[srow * 72 + scol * 4] = khv;
            *(f16x4*)&kL[srow * 72 + scol * 4] = klv;
        }
        #pragma unroll
        for (int u = 0; u < 4; ++u) {
            float vv = (&v4.x)[u];
            f16 vh, vl;
            splitf(vv, vh, vl);
            const int idx = (scol * 4 + u) * 40 + ((sG ^ vgW) << 3) + sIn;
            vTH[idx] = vh;
            vTL[idx] = vl;
        }
        __syncthreads();

        f16x8 aH[2], aL[2];
        #pragma unroll
        for (int ks = 0; ks < 2; ++ks) {
            aH[ks] = *(const f16x8*)&kH[(st * 16 + m) * 72 + ks * 32 + quad * 8];
            aL[ks] = *(const f16x8*)&kL[(st * 16 + m) * 72 + ks * 32 + quad * 8];
        }
        const float4 c4 = *(const float4*)&cS[st * 16 + quad * 4];
        const int mG = (m >> 2) & 3;                     // (f>>2)&3 and (d>>2)&3 for lane m
        const int pG = ((st * 2 + (quad >> 1)) ^ mG);    // swizzled s-granule for pT write
        const int pOff = (pG << 3) + ((quad & 1) << 2);
        #pragma unroll
        for (int ff = 0; ff < 4; ++ff) {
            f32x4 acc = (f32x4){0.f, 0.f, 0.f, 0.f};
            #pragma unroll
            for (int ks = 0; ks < 2; ++ks) {
                acc = __builtin_amdgcn_mfma_f32_16x16x32_f16(aH[ks], wbH[ff][ks], acc, 0, 0, 0);
                acc = __builtin_amdgcn_mfma_f32_16x16x32_f16(aH[ks], wbL[ff][ks], acc, 0, 0, 0);
                acc = __builtin_amdgcn_mfma_f32_16x16x32_f16(aL[ks], wbH[ff][ks], acc, 0, 0, 0);
            }
            float ksp = 0.f;
            f16x4 phv, plv;
            #pragma unroll
            for (int r = 0; r < 4; ++r) {
                float d = acc[r];
                dmax = fmaxf(dmax, d);
                float p = __expf(d - (&c4.x)[r] - mhat) * FSCALE;
                ksp += p;
                f16 h, lo;
                splitf(p, h, lo);
                phv[r] = h; plv[r] = lo;
            }
            const int f = (fgroup * 4 + ff) * 16 + m;
            *(f16x4*)&pTH[f * 40 + pOff] = phv;
            *(f16x4*)&pTL[f * 40 + pOff] = plv;
            ksp += __shfl_xor(ksp, 16);
            ksp += __shfl_xor(ksp, 32);
            ksacc[ff] += ksp;
        }
        __syncthreads();

        if (it < 15) {
            k4 = kg[(rbase + (it + 1) * 32 + srow) * 16 + scol];
            v4 = vg[(rbase + (it + 1) * 32 + srow) * 16 + scol];
        }

        f16x8 aH2[2], aL2[2], bH2[4], bL2[4];
        #pragma unroll
        for (int tt = 0; tt < 2; ++tt) {
            const int f = (wid * 2 + tt) * 16 + m;
            const int off = f * 40 + ((quad ^ mG) << 3);
            aH2[tt] = *(const f16x8*)&pTH[off];
            aL2[tt] = *(const f16x8*)&pTL[off];
        }
        #pragma unroll
        for (int dtile = 0; dtile < 4; ++dtile) {
            const int d = dtile * 16 + m;
            const int off = d * 40 + ((quad ^ mG) << 3);
            bH2[dtile] = *(const f16x8*)&vTH[off];
            bL2[dtile] = *(const f16x8*)&vTL[off];
        }
        #pragma unroll
        for (int tt = 0; tt < 2; ++tt) {
            #pragma unroll
            for (int dtile = 0; dtile < 4; ++dtile) {
                f32x4 a = acc2[tt * 4 + dtile];
                a = __builtin_amdgcn_mfma_f32_16x16x32_f16(aH2[tt], bH2[dtile], a, 0, 0, 0);
                a = __builtin_amdgcn_mfma_f32_16x16x32_f16(aH2[tt], bL2[dtile], a, 0, 0, 0);
                a = __builtin_amdgcn_mfma_f32_16x16x32_f16(aL2[tt], bH2[dtile], a, 0, 0, 0);
                acc2[tt * 4 + dtile] = a;
            }
        }
        __syncthreads();
    }

    #pragma unroll
    for (int tt = 0; tt < 2; ++tt) {
        #pragma unroll
        for (int dtile = 0; dtile < 4; ++dtile) {
            #pragma unroll
            for (int r = 0; r < 4; ++r) {
                const int f = (wid * 2 + tt) * 16 + quad * 4 + r;
                const int d = dtile * 16 + m;
                atomicAdd(&kv[((size_t)b * FF + f) * DD + d], acc2[tt * 4 + dtile][r]);
            }
        }
    }
    if (l < 16) {
        #pragma unroll
        for (int ff = 0; ff < 4; ++ff)
            atomicAdd(&ksum[b * FF + (fgroup * 4 + ff) * 16 + l], ksacc[ff]);
    }
    #pragma unroll
    for (int off = 32; off; off >>= 1) dmax = fmaxf(dmax, __shfl_xor(dmax, off));
    if (l == 0) redw[wid] = dmax;
    __syncthreads();
    if (t == 0) {
        float mx = redw[0];
        #pragma unroll
        for (int i = 1; i < 8; ++i) mx = fmaxf(mx, redw[i]);
        atomicMax(&mkey[b], fkey(mx));
    }
}

// ---------------------------------------------------------------------------
// K3 (MFMA): out = phi_q . kv / deno. (unchanged — proven)
// ---------------------------------------------------------------------------
__global__ __launch_bounds__(512, 2) void k_out(const float* __restrict__ qin,
                                                const float* __restrict__ w,
                                                const float* __restrict__ ws,
                                                float* __restrict__ outp) {
    const float* kv = ws + KV_OFF_F;
    const float* ksum = ws + KSUM_OFF_F;
    const unsigned* mkey = (const unsigned*)ws + MKEY_OFF_F;
    const unsigned* nkey = (const unsigned*)ws + NKEY_OFF_F;
    const float* msum = ws + MSUM_OFF_F;

    const int b = blockIdx.y, chunk = blockIdx.x, t = threadIdx.x;
    const int wid = t >> 6, l = t & 63, quad = l >> 4, m = l & 15;
    const int st = wid & 1, fgroup = wid >> 1;   // phase A: (s-tile, f-group)
    const int dt = wid >> 1;                     // phase B: (s-tile=st, d-tile)

    __shared__ __align__(16) f16 qH[32 * 72], qL[32 * 72];
    __shared__ __align__(16) f16 pH[32 * 264], pL[32 * 264];
    __shared__ __align__(16) float oL[32 * 68];
    __shared__ float cS[32], mqL[32];
    __shared__ float ksL[256];
    __shared__ float denoP[4][32], dmaxP[4][32];
    __shared__ float scaleL[32];
    __shared__ float abL;

    if (t < 64) {
        float mv = msum[b * DD + t] * (1.0f / 4096.0f);
        float sq = mv * mv;
        #pragma unroll
        for (int off = 32; off; off >>= 1) sq += __shfl_xor(sq, off);
        if (t == 0) {
            float mhat = (sqrtf(funkey(nkey[b])) + sqrtf(sq)) * INVS;  // same ops as k_kv
            abL = __expf(mhat - funkey(mkey[b]));                      // alpha_b >= 1
        }
    }
    if (t < 256) ksL[t] = ksum[b * FF + t];

    f16x8 wbH[4][2], wbL[4][2];
    #pragma unroll
    for (int ff = 0; ff < 4; ++ff) {
        #pragma unroll
        for (int ks = 0; ks < 2; ++ks) {
            const float* wp = w + (((fgroup * 4 + ff) * 16 + m) * 64 + ks * 32 + quad * 8);
            float4 x0 = *(const float4*)wp;
            float4 x1 = *(const float4*)(wp + 4);
            f16 h, lo;
            splitf(x0.x, h, lo); wbH[ff][ks][0] = h; wbL[ff][ks][0] = lo;
            splitf(x0.y, h, lo); wbH[ff][ks][1] = h; wbL[ff][ks][1] = lo;
            splitf(x0.z, h, lo); wbH[ff][ks][2] = h; wbL[ff][ks][2] = lo;
            splitf(x0.w, h, lo); wbH[ff][ks][3] = h; wbL[ff][ks][3] = lo;
            splitf(x1.x, h, lo); wbH[ff][ks][4] = h; wbL[ff][ks][4] = lo;
            splitf(x1.y, h, lo); wbH[ff][ks][5] = h; wbL[ff][ks][5] = lo;
            splitf(x1.z, h, lo); wbH[ff][ks][6] = h; wbL[ff][ks][6] = lo;
            splitf(x1.w, h, lo); wbH[ff][ks][7] = h; wbL[ff][ks][7] = lo;
        }
    }

    f16x8 kvH[8], kvL[8];
    {
        const float* kvg = kv + (size_t)b * (FF * DD) + dt * 16 + m;
        #pragma unroll
        for (int ks = 0; ks < 8; ++ks) {
            #pragma unroll
            for (int j = 0; j < 8; ++j) {
                float x = kvg[(ks * 32 + quad * 8 + j) * 64];
                f16 h, lo;
                splitf(x, h, lo);
                kvH[ks][j] = h; kvL[ks][j] = lo;
            }
        }
    }
    __syncthreads();

    const int srow = t >> 4, scol = t & 15;
    const int rbase = chunk * 512;
    const float4* qg = (const float4*)qin + (size_t)b * (SS * 16);
    float4* og = (float4*)outp + (size_t)b * (SS * 16);

    float4 q4 = qg[(rbase + srow) * 16 + scol];

    for (int it = 0; it < 16; ++it) {
        float4 qs;
        qs.x = q4.x * INVS; qs.y = q4.y * INVS;
        qs.z = q4.z * INVS; qs.w = q4.w * INVS;
        float sq = qs.x * qs.x + qs.y * qs.y + qs.z * qs.z + qs.w * qs.w;
        #pragma unroll
        for (int off = 1; off <= 8; off <<= 1) sq += __shfl_xor(sq, off);
        if (scol == 0) { cS[srow] = 0.5f * sq; mqL[srow] = sqrtf(sq); }
        {
            f16x4 hv, lv;
            f16 h, lo;
            splitf(qs.x, h, lo); hv[0] = h; lv[0] = lo;
            splitf(qs.y, h, lo); hv[1] = h; lv[1] = lo;
            splitf(qs.z, h, lo); hv[2] = h; lv[2] = lo;
            splitf(qs.w, h, lo); hv[3] = h; lv[3] = lo;
            *(f16x4*)&qH[srow * 72 + scol * 4] = hv;
            *(f16x4*)&qL[srow * 72 + scol * 4] = lv;
        }
        __syncthreads();

        f16x8 bqH[2], bqL[2];
        #pragma unroll
        for (int ks = 0; ks < 2; ++ks) {
            bqH[ks] = *(const f16x8*)&qH[(st * 16 + m) * 72 + ks * 32 + quad * 8];
            bqL[ks] = *(const f16x8*)&qL[(st * 16 + m) * 72 + ks * 32 + quad * 8];
        }
        const float cs = cS[st * 16 + m];
        const float mq = mqL[st * 16 + m];
        float dpart = 0.f, dmax = -1e30f;
        #pragma unroll
        for (int ff = 0; ff < 4; ++ff) {
            f32x4 acc = (f32x4){0.f, 0.f, 0.f, 0.f};
            #pragma unroll
            for (int ks = 0; ks < 2; ++ks) {
                acc = __builtin_amdgcn_mfma_f32_16x16x32_f16(wbH[ff][ks], bqH[ks], acc, 0, 0, 0);
                acc = __builtin_amdgcn_mfma_f32_16x16x32_f16(wbH[ff][ks], bqL[ks], acc, 0, 0, 0);
                acc = __builtin_amdgcn_mfma_f32_16x16x32_f16(wbL[ff][ks], bqH[ks], acc, 0, 0, 0);
            }
            const int f0 = (fgroup * 4 + ff) * 16 + quad * 4;
            const float4 ksv = *(const float4*)&ksL[f0];
            f16x4 phv, plv;
            #pragma unroll
            for (int r = 0; r < 4; ++r) {
                float d = acc[r];
                dmax = fmaxf(dmax, d);
                float p = __expf(d - cs - mq);      // FSCALE folded into A later
                dpart = fmaf(p, (&ksv.x)[r], dpart);
                f16 h, lo;
                splitf(p, h, lo);
                phv[r] = h; plv[r] = lo;
            }
            *(f16x4*)&pH[(st * 16 + m) * 264 + f0] = phv;
            *(f16x4*)&pL[(st * 16 + m) * 264 + f0] = plv;
        }
        dpart += __shfl_xor(dpart, 16);
        dpart += __shfl_xor(dpart, 32);
        dmax = fmaxf(dmax, __shfl_xor(dmax, 16));
        dmax = fmaxf(dmax, __shfl_xor(dmax, 32));
        if (l < 16) {
            denoP[fgroup][st * 16 + l] = dpart;
            dmaxP[fgroup][st * 16 + l] = dmax;
        }
        __syncthreads();

        if (t < 32) {
            float dn0 = denoP[0][t] + denoP[1][t] + denoP[2][t] + denoP[3][t];
            float mt = fmaxf(fmaxf(dmaxP[0][t], dmaxP[1][t]),
                             fmaxf(dmaxP[2][t], dmaxP[3][t]));
            float A = abL * __expf(mqL[t] - mt) * FSCALE;
            float dn = fmaxf(A * dn0, 1e-4f);
            scaleL[t] = A / dn;
        }
        if (it < 15) q4 = qg[(rbase + (it + 1) * 32 + srow) * 16 + scol];

        f32x4 acc2 = (f32x4){0.f, 0.f, 0.f, 0.f};
        #pragma unroll
        for (int ks = 0; ks < 8; ++ks) {
            f16x8 paH = *(const f16x8*)&pH[(st * 16 + m) * 264 + ks * 32 + quad * 8];
            f16x8 paL = *(const f16x8*)&pL[(st * 16 + m) * 264 + ks * 32 + quad * 8];
            acc2 = __builtin_amdgcn_mfma_f32_16x16x32_f16(paH, kvH[ks], acc2, 0, 0, 0);
            acc2 = __builtin_amdgcn_mfma_f32_16x16x32_f16(paH, kvL[ks], acc2, 0, 0, 0);
            acc2 = __builtin_amdgcn_mfma_f32_16x16x32_f16(paL, kvH[ks], acc2, 0, 0, 0);
        }
        #pragma unroll
        for (int r = 0; r < 4; ++r)
            oL[(st * 16 + quad * 4 + r) * 68 + dt * 16 + m] = acc2[r];
        __syncthreads();

        {
            float4 ov = *(const float4*)&oL[srow * 68 + scol * 4];
            float s = scaleL[srow];
            og[(rbase + it * 32 + srow) * 16 + scol] =
                make_float4(ov.x * s, ov.y * s, ov.z * s, ov.w * s);
        }
    }
}

extern "C" void kernel_launch(void* const* d_in, const int* in_sizes, int n_in,
                              void* d_out, int out_size, void* d_ws, size_t ws_size,
                              hipStream_t stream) {
    (void)in_sizes; (void)n_in; (void)out_size; (void)ws_size;
    const float* q = (const float*)d_in[0];
    const float* k = (const float*)d_in[1];
    const float* v = (const float*)d_in[2];
    const float* w = (const float*)d_in[3];
    float* out = (float*)d_out;
    float* ws = (float*)d_ws;

    hipMemsetAsync(d_ws, 0, WS_ZERO_BYTES, stream);
    k_stats<<<dim3(16, 64), 256, 0, stream>>>(k, ws + MSUM_OFF_F, (unsigned*)ws + NKEY_OFF_F);
    k_kv<<<dim3(8, 64), 512, 0, stream>>>(k, v, w, ws);
    k_out<<<dim3(8, 64), 512, 0, stream>>>(q, w, ws, out);
}

// Round 4
// 376.844 us; speedup vs baseline: 1.2949x; 1.0064x over previous
//
#include <hip/hip_runtime.h>

#define BB 64
#define SS 4096
#define DD 64
#define FF 256
#define INVS 0.35355339059327373f   // 1/sqrt(8) = 64^-0.25
#define FSCALE 0.0625f              // 256^-0.5

// workspace layout (float-index offsets)
#define KV_OFF_F    0                          // [BB][FF][DD]
#define KSUM_OFF_F  (BB*FF*DD)                 // [BB][FF]
#define MKEY_OFF_F  (KSUM_OFF_F + BB*FF)       // [BB] uint keys (true max k_proj)
#define NKEY_OFF_F  (MKEY_OFF_F + BB)          // [BB] uint keys (max raw row |k|^2)
#define MSUM_OFF_F  (NKEY_OFF_F + BB)          // [BB][DD] column sums of raw k
#define WS_ZERO_F   (MSUM_OFF_F + BB*DD)
#define WS_ZERO_BYTES (WS_ZERO_F * 4)

typedef _Float16 f16;
typedef __attribute__((ext_vector_type(4))) _Float16 f16x4;
typedef __attribute__((ext_vector_type(8))) _Float16 f16x8;
typedef __attribute__((ext_vector_type(4))) float f32x4;

__device__ __forceinline__ unsigned fkey(float f) {
    unsigned b = __float_as_uint(f);
    return (f < 0.0f) ? ~b : (b | 0x80000000u);
}
__device__ __forceinline__ float funkey(unsigned k) {
    return (k & 0x80000000u) ? __uint_as_float(k ^ 0x80000000u) : __uint_as_float(~k);
}
__device__ __forceinline__ void splitf(float x, f16& h, f16& l) {
    h = (f16)x;
    l = (f16)(x - (float)h);
}

// ---------------------------------------------------------------------------
// K1: per-b column sums of raw k (mean) + max raw row-norm^2. (unchanged)
// ---------------------------------------------------------------------------
__global__ __launch_bounds__(256) void k_stats(const float* __restrict__ kin,
                                               float* __restrict__ msum,
                                               unsigned* __restrict__ nkey) {
    const int b = blockIdx.y, chunk = blockIdx.x;
    const int t = threadIdx.x, row = t >> 4, c16 = t & 15;
    const float4* kg = (const float4*)(kin + (size_t)b * (SS * DD));
    float4 cacc = make_float4(0.f, 0.f, 0.f, 0.f);
    float nmax = 0.f;
    const int s0 = chunk * 256;
    #pragma unroll 4
    for (int it = 0; it < 16; ++it) {
        const int s = s0 + it * 16 + row;
        float4 x = kg[s * 16 + c16];
        cacc.x += x.x; cacc.y += x.y; cacc.z += x.z; cacc.w += x.w;
        float sq = x.x * x.x + x.y * x.y + x.z * x.z + x.w * x.w;
        #pragma unroll
        for (int off = 1; off <= 8; off <<= 1) sq += __shfl_xor(sq, off);
        nmax = fmaxf(nmax, sq);
    }
    __shared__ float csum[64];
    __shared__ float wm[4];
    if (t < 64) csum[t] = 0.f;
    __syncthreads();
    atomicAdd(&csum[c16 * 4 + 0], cacc.x);
    atomicAdd(&csum[c16 * 4 + 1], cacc.y);
    atomicAdd(&csum[c16 * 4 + 2], cacc.z);
    atomicAdd(&csum[c16 * 4 + 3], cacc.w);
    nmax = fmaxf(nmax, __shfl_xor(nmax, 16));
    nmax = fmaxf(nmax, __shfl_xor(nmax, 32));
    if ((t & 63) == 0) wm[t >> 6] = nmax;
    __syncthreads();
    if (t < 64) atomicAdd(&msum[b * DD + t], csum[t]);
    if (t == 0) {
        float mx = fmaxf(fmaxf(wm[0], wm[1]), fmaxf(wm[2], wm[3]));
        atomicMax(&nkey[b], fkey(mx));
    }
}

// ---------------------------------------------------------------------------
// K2 (MFMA): phi_k^T V.
// Round-4: register-pressure re-mapping for true 2 blocks/CU without spills.
// Each wave now owns 2 f-tiles for BOTH s-tiles in phase A (was 4 f-tiles,
// one s-tile): W frags 64->32 VGPRs. Phase-B b-frag loads split into 2
// chunks (transient peak 48->32). Target total (VGPR+AGPR) <= 128 so
// 16 waves/CU fit. Keeps swizzle + register ksum. grid (8,64).
// ---------------------------------------------------------------------------
__global__ __launch_bounds__(512, 1) void k_kv(const float* __restrict__ kin,
                                               const float* __restrict__ vin,
                                               const float* __restrict__ w,
                                               float* __restrict__ ws) {
    float* kv = ws + KV_OFF_F;
    float* ksum = ws + KSUM_OFF_F;
    unsigned* mkey = (unsigned*)ws + MKEY_OFF_F;
    const unsigned* nkey = (const unsigned*)ws + NKEY_OFF_F;
    const float* msum = ws + MSUM_OFF_F;

    const int b = blockIdx.y, chunk = blockIdx.x;
    const int t = threadIdx.x;
    const int wid = t >> 6, l = t & 63, quad = l >> 4, m = l & 15;

    __shared__ __align__(16) f16 kH[32 * 72], kL[32 * 72];
    __shared__ __align__(16) f16 vTH[64 * 40], vTL[64 * 40];
    __shared__ __align__(16) f16 pTH[256 * 40], pTL[256 * 40];
    __shared__ __align__(16) float cS[32];
    __shared__ __align__(16) float muL[64];
    __shared__ float redw[8];
    __shared__ float mhatL;

    if (t < 64) {
        float mv = msum[b * DD + t] * (1.0f / 4096.0f);
        muL[t] = mv;
        float sq = mv * mv;
        #pragma unroll
        for (int off = 32; off; off >>= 1) sq += __shfl_xor(sq, off);
        if (t == 0) mhatL = (sqrtf(funkey(nkey[b])) + sqrtf(sq)) * INVS;
    }

    // W fragments: wave wid owns f-tiles {2*wid, 2*wid+1}.
    f16x8 wbH[2][2], wbL[2][2];
    #pragma unroll
    for (int ff = 0; ff < 2; ++ff) {
        #pragma unroll
        for (int ks = 0; ks < 2; ++ks) {
            const float* wp = w + (((wid * 2 + ff) * 16 + m) * 64 + ks * 32 + quad * 8);
            float4 x0 = *(const float4*)wp;
            float4 x1 = *(const float4*)(wp + 4);
            f16 h, lo;
            splitf(x0.x, h, lo); wbH[ff][ks][0] = h; wbL[ff][ks][0] = lo;
            splitf(x0.y, h, lo); wbH[ff][ks][1] = h; wbL[ff][ks][1] = lo;
            splitf(x0.z, h, lo); wbH[ff][ks][2] = h; wbL[ff][ks][2] = lo;
            splitf(x0.w, h, lo); wbH[ff][ks][3] = h; wbL[ff][ks][3] = lo;
            splitf(x1.x, h, lo); wbH[ff][ks][4] = h; wbL[ff][ks][4] = lo;
            splitf(x1.y, h, lo); wbH[ff][ks][5] = h; wbL[ff][ks][5] = lo;
            splitf(x1.z, h, lo); wbH[ff][ks][6] = h; wbL[ff][ks][6] = lo;
            splitf(x1.w, h, lo); wbH[ff][ks][7] = h; wbL[ff][ks][7] = lo;
        }
    }
    __syncthreads();
    const float mhat = mhatL;
    const int srow = t >> 4, scol = t & 15;
    const float4 mu4 = *(const float4*)&muL[scol * 4];

    f32x4 acc2[8];
    #pragma unroll
    for (int i = 0; i < 8; ++i) acc2[i] = (f32x4){0.f, 0.f, 0.f, 0.f};
    float ksacc[2] = {0.f, 0.f};
    float dmax = -1e30f;

    const int rbase = chunk * 512;
    const float4* kg = (const float4*)(kin + (size_t)b * (SS * DD));
    const float4* vg = (const float4*)(vin + (size_t)b * (SS * DD));

    float4 k4 = kg[(rbase + srow) * 16 + scol];
    float4 v4 = vg[(rbase + srow) * 16 + scol];

    // staging-side swizzle constants
    const int vgW = scol & 3;            // (d>>2)&3 for d = scol*4+u
    const int sG = srow >> 3, sIn = srow & 7;
    const int mG = (m >> 2) & 3;         // (f>>2)&3 and (d>>2)&3 for lane m

    for (int it = 0; it < 16; ++it) {
        // ---- stage current regs -> LDS ----
        float4 kc;
        kc.x = (k4.x - mu4.x) * INVS; kc.y = (k4.y - mu4.y) * INVS;
        kc.z = (k4.z - mu4.z) * INVS; kc.w = (k4.w - mu4.w) * INVS;
        float sq = kc.x * kc.x + kc.y * kc.y + kc.z * kc.z + kc.w * kc.w;
        #pragma unroll
        for (int off = 1; off <= 8; off <<= 1) sq += __shfl_xor(sq, off);
        if (scol == 0) cS[srow] = 0.5f * sq;
        {
            f16x4 khv, klv;
            f16 h, lo;
            splitf(kc.x, h, lo); khv[0] = h; klv[0] = lo;
            splitf(kc.y, h, lo); khv[1] = h; klv[1] = lo;
            splitf(kc.z, h, lo); khv[2] = h; klv[2] = lo;
            splitf(kc.w, h, lo); khv[3] = h; klv[3] = lo;
            *(f16x4*)&kH[srow * 72 + scol * 4] = khv;
            *(f16x4*)&kL[srow * 72 + scol * 4] = klv;
        }
        #pragma unroll
        for (int u = 0; u < 4; ++u) {
            float vv = (&v4.x)[u];
            f16 vh, vl;
            splitf(vv, vh, vl);
            const int idx = (scol * 4 + u) * 40 + ((sG ^ vgW) << 3) + sIn;
            vTH[idx] = vh;
            vTL[idx] = vl;
        }
        __syncthreads();

        // ---- phase A: both s-tiles, 2 f-tiles per wave ----
        #pragma unroll
        for (int st = 0; st < 2; ++st) {
            f16x8 aH[2], aL[2];
            #pragma unroll
            for (int ks = 0; ks < 2; ++ks) {
                aH[ks] = *(const f16x8*)&kH[(st * 16 + m) * 72 + ks * 32 + quad * 8];
                aL[ks] = *(const f16x8*)&kL[(st * 16 + m) * 72 + ks * 32 + quad * 8];
            }
            const float4 c4 = *(const float4*)&cS[st * 16 + quad * 4];
            const int pG = ((st * 2 + (quad >> 1)) ^ mG);    // swizzled s-granule
            const int pOff = (pG << 3) + ((quad & 1) << 2);
            #pragma unroll
            for (int ff = 0; ff < 2; ++ff) {
                f32x4 acc = (f32x4){0.f, 0.f, 0.f, 0.f};
                #pragma unroll
                for (int ks = 0; ks < 2; ++ks) {
                    acc = __builtin_amdgcn_mfma_f32_16x16x32_f16(aH[ks], wbH[ff][ks], acc, 0, 0, 0);
                    acc = __builtin_amdgcn_mfma_f32_16x16x32_f16(aH[ks], wbL[ff][ks], acc, 0, 0, 0);
                    acc = __builtin_amdgcn_mfma_f32_16x16x32_f16(aL[ks], wbH[ff][ks], acc, 0, 0, 0);
                }
                float ksp = 0.f;
                f16x4 phv, plv;
                #pragma unroll
                for (int r = 0; r < 4; ++r) {
                    float d = acc[r];
                    dmax = fmaxf(dmax, d);
                    float p = __expf(d - (&c4.x)[r] - mhat) * FSCALE;
                    ksp += p;
                    f16 h, lo;
                    splitf(p, h, lo);
                    phv[r] = h; plv[r] = lo;
                }
                const int f = (wid * 2 + ff) * 16 + m;
                *(f16x4*)&pTH[f * 40 + pOff] = phv;
                *(f16x4*)&pTL[f * 40 + pOff] = plv;
                ksp += __shfl_xor(ksp, 16);
                ksp += __shfl_xor(ksp, 32);
                ksacc[ff] += ksp;
            }
        }
        __syncthreads();

        // prefetch next stage (overlaps phase B)
        if (it < 15) {
            k4 = kg[(rbase + (it + 1) * 32 + srow) * 16 + scol];
            v4 = vg[(rbase + (it + 1) * 32 + srow) * 16 + scol];
        }

        // ---- phase B: kv += P^T * V, b-frags loaded in 2 chunks ----
        f16x8 aH2[2], aL2[2];
        #pragma unroll
        for (int tt = 0; tt < 2; ++tt) {
            const int f = (wid * 2 + tt) * 16 + m;
            const int off = f * 40 + ((quad ^ mG) << 3);
            aH2[tt] = *(const f16x8*)&pTH[off];
            aL2[tt] = *(const f16x8*)&pTL[off];
        }
        #pragma unroll
        for (int dh = 0; dh < 2; ++dh) {
            f16x8 bH2[2], bL2[2];
            #pragma unroll
            for (int dj = 0; dj < 2; ++dj) {
                const int d = (dh * 2 + dj) * 16 + m;
                const int off = d * 40 + ((quad ^ mG) << 3);
                bH2[dj] = *(const f16x8*)&vTH[off];
                bL2[dj] = *(const f16x8*)&vTL[off];
            }
            #pragma unroll
            for (int tt = 0; tt < 2; ++tt) {
                #pragma unroll
                for (int dj = 0; dj < 2; ++dj) {
                    f32x4 a = acc2[tt * 4 + dh * 2 + dj];
                    a = __builtin_amdgcn_mfma_f32_16x16x32_f16(aH2[tt], bH2[dj], a, 0, 0, 0);
                    a = __builtin_amdgcn_mfma_f32_16x16x32_f16(aH2[tt], bL2[dj], a, 0, 0, 0);
                    a = __builtin_amdgcn_mfma_f32_16x16x32_f16(aL2[tt], bH2[dj], a, 0, 0, 0);
                    acc2[tt * 4 + dh * 2 + dj] = a;
                }
            }
        }
        __syncthreads();
    }

    // ---- epilogue ----
    #pragma unroll
    for (int tt = 0; tt < 2; ++tt) {
        #pragma unroll
        for (int dtile = 0; dtile < 4; ++dtile) {
            #pragma unroll
            for (int r = 0; r < 4; ++r) {
                const int f = (wid * 2 + tt) * 16 + quad * 4 + r;
                const int d = dtile * 16 + m;
                atomicAdd(&kv[((size_t)b * FF + f) * DD + d], acc2[tt * 4 + dtile][r]);
            }
        }
    }
    if (l < 16) {
        #pragma unroll
        for (int ff = 0; ff < 2; ++ff)
            atomicAdd(&ksum[b * FF + (wid * 2 + ff) * 16 + l], ksacc[ff]);
    }
    #pragma unroll
    for (int off = 32; off; off >>= 1) dmax = fmaxf(dmax, __shfl_xor(dmax, off));
    if (l == 0) redw[wid] = dmax;
    __syncthreads();
    if (t == 0) {
        float mx = redw[0];
        #pragma unroll
        for (int i = 1; i < 8; ++i) mx = fmaxf(mx, redw[i]);
        atomicMax(&mkey[b], fkey(mx));
    }
}

// ---------------------------------------------------------------------------
// K3 (MFMA): out = phi_q . kv / deno. (unchanged — proven)
// ---------------------------------------------------------------------------
__global__ __launch_bounds__(512, 2) void k_out(const float* __restrict__ qin,
                                                const float* __restrict__ w,
                                                const float* __restrict__ ws,
                                                float* __restrict__ outp) {
    const float* kv = ws + KV_OFF_F;
    const float* ksum = ws + KSUM_OFF_F;
    const unsigned* mkey = (const unsigned*)ws + MKEY_OFF_F;
    const unsigned* nkey = (const unsigned*)ws + NKEY_OFF_F;
    const float* msum = ws + MSUM_OFF_F;

    const int b = blockIdx.y, chunk = blockIdx.x, t = threadIdx.x;
    const int wid = t >> 6, l = t & 63, quad = l >> 4, m = l & 15;
    const int st = wid & 1, fgroup = wid >> 1;   // phase A: (s-tile, f-group)
    const int dt = wid >> 1;                     // phase B: (s-tile=st, d-tile)

    __shared__ __align__(16) f16 qH[32 * 72], qL[32 * 72];
    __shared__ __align__(16) f16 pH[32 * 264], pL[32 * 264];
    __shared__ __align__(16) float oL[32 * 68];
    __shared__ float cS[32], mqL[32];
    __shared__ float ksL[256];
    __shared__ float denoP[4][32], dmaxP[4][32];
    __shared__ float scaleL[32];
    __shared__ float abL;

    if (t < 64) {
        float mv = msum[b * DD + t] * (1.0f / 4096.0f);
        float sq = mv * mv;
        #pragma unroll
        for (int off = 32; off; off >>= 1) sq += __shfl_xor(sq, off);
        if (t == 0) {
            float mhat = (sqrtf(funkey(nkey[b])) + sqrtf(sq)) * INVS;  // same ops as k_kv
            abL = __expf(mhat - funkey(mkey[b]));                      // alpha_b >= 1
        }
    }
    if (t < 256) ksL[t] = ksum[b * FF + t];

    f16x8 wbH[4][2], wbL[4][2];
    #pragma unroll
    for (int ff = 0; ff < 4; ++ff) {
        #pragma unroll
        for (int ks = 0; ks < 2; ++ks) {
            const float* wp = w + (((fgroup * 4 + ff) * 16 + m) * 64 + ks * 32 + quad * 8);
            float4 x0 = *(const float4*)wp;
            float4 x1 = *(const float4*)(wp + 4);
            f16 h, lo;
            splitf(x0.x, h, lo); wbH[ff][ks][0] = h; wbL[ff][ks][0] = lo;
            splitf(x0.y, h, lo); wbH[ff][ks][1] = h; wbL[ff][ks][1] = lo;
            splitf(x0.z, h, lo); wbH[ff][ks][2] = h; wbL[ff][ks][2] = lo;
            splitf(x0.w, h, lo); wbH[ff][ks][3] = h; wbL[ff][ks][3] = lo;
            splitf(x1.x, h, lo); wbH[ff][ks][4] = h; wbL[ff][ks][4] = lo;
            splitf(x1.y, h, lo); wbH[ff][ks][5] = h; wbL[ff][ks][5] = lo;
            splitf(x1.z, h, lo); wbH[ff][ks][6] = h; wbL[ff][ks][6] = lo;
            splitf(x1.w, h, lo); wbH[ff][ks][7] = h; wbL[ff][ks][7] = lo;
        }
    }

    f16x8 kvH[8], kvL[8];
    {
        const float* kvg = kv + (size_t)b * (FF * DD) + dt * 16 + m;
        #pragma unroll
        for (int ks = 0; ks < 8; ++ks) {
            #pragma unroll
            for (int j = 0; j < 8; ++j) {
                float x = kvg[(ks * 32 + quad * 8 + j) * 64];
                f16 h, lo;
                splitf(x, h, lo);
                kvH[ks][j] = h; kvL[ks][j] = lo;
            }
        }
    }
    __syncthreads();

    const int srow = t >> 4, scol = t & 15;
    const int rbase = chunk * 512;
    const float4* qg = (const float4*)qin + (size_t)b * (SS * 16);
    float4* og = (float4*)outp + (size_t)b * (SS * 16);

    float4 q4 = qg[(rbase + srow) * 16 + scol];

    for (int it = 0; it < 16; ++it) {
        float4 qs;
        qs.x = q4.x * INVS; qs.y = q4.y * INVS;
        qs.z = q4.z * INVS; qs.w = q4.w * INVS;
        float sq = qs.x * qs.x + qs.y * qs.y + qs.z * qs.z + qs.w * qs.w;
        #pragma unroll
        for (int off = 1; off <= 8; off <<= 1) sq += __shfl_xor(sq, off);
        if (scol == 0) { cS[srow] = 0.5f * sq; mqL[srow] = sqrtf(sq); }
        {
            f16x4 hv, lv;
            f16 h, lo;
            splitf(qs.x, h, lo); hv[0] = h; lv[0] = lo;
            splitf(qs.y, h, lo); hv[1] = h; lv[1] = lo;
            splitf(qs.z, h, lo); hv[2] = h; lv[2] = lo;
            splitf(qs.w, h, lo); hv[3] = h; lv[3] = lo;
            *(f16x4*)&qH[srow * 72 + scol * 4] = hv;
            *(f16x4*)&qL[srow * 72 + scol * 4] = lv;
        }
        __syncthreads();

        f16x8 bqH[2], bqL[2];
        #pragma unroll
        for (int ks = 0; ks < 2; ++ks) {
            bqH[ks] = *(const f16x8*)&qH[(st * 16 + m) * 72 + ks * 32 + quad * 8];
            bqL[ks] = *(const f16x8*)&qL[(st * 16 + m) * 72 + ks * 32 + quad * 8];
        }
        const float cs = cS[st * 16 + m];
        const float mq = mqL[st * 16 + m];
        float dpart = 0.f, dmax = -1e30f;
        #pragma unroll
        for (int ff = 0; ff < 4; ++ff) {
            f32x4 acc = (f32x4){0.f, 0.f, 0.f, 0.f};
            #pragma unroll
            for (int ks = 0; ks < 2; ++ks) {
                acc = __builtin_amdgcn_mfma_f32_16x16x32_f16(wbH[ff][ks], bqH[ks], acc, 0, 0, 0);
                acc = __builtin_amdgcn_mfma_f32_16x16x32_f16(wbH[ff][ks], bqL[ks], acc, 0, 0, 0);
                acc = __builtin_amdgcn_mfma_f32_16x16x32_f16(wbL[ff][ks], bqH[ks], acc, 0, 0, 0);
            }
            const int f0 = (fgroup * 4 + ff) * 16 + quad * 4;
            const float4 ksv = *(const float4*)&ksL[f0];
            f16x4 phv, plv;
            #pragma unroll
            for (int r = 0; r < 4; ++r) {
                float d = acc[r];
                dmax = fmaxf(dmax, d);
                float p = __expf(d - cs - mq);      // FSCALE folded into A later
                dpart = fmaf(p, (&ksv.x)[r], dpart);
                f16 h, lo;
                splitf(p, h, lo);
                phv[r] = h; plv[r] = lo;
            }
            *(f16x4*)&pH[(st * 16 + m) * 264 + f0] = phv;
            *(f16x4*)&pL[(st * 16 + m) * 264 + f0] = plv;
        }
        dpart += __shfl_xor(dpart, 16);
        dpart += __shfl_xor(dpart, 32);
        dmax = fmaxf(dmax, __shfl_xor(dmax, 16));
        dmax = fmaxf(dmax, __shfl_xor(dmax, 32));
        if (l < 16) {
            denoP[fgroup][st * 16 + l] = dpart;
            dmaxP[fgroup][st * 16 + l] = dmax;
        }
        __syncthreads();

        if (t < 32) {
            float dn0 = denoP[0][t] + denoP[1][t] + denoP[2][t] + denoP[3][t];
            float mt = fmaxf(fmaxf(dmaxP[0][t], dmaxP[1][t]),
                             fmaxf(dmaxP[2][t], dmaxP[3][t]));
            float A = abL * __expf(mqL[t] - mt) * FSCALE;
            float dn = fmaxf(A * dn0, 1e-4f);
            scaleL[t] = A / dn;
        }
        if (it < 15) q4 = qg[(rbase + (it + 1) * 32 + srow) * 16 + scol];

        f32x4 acc2 = (f32x4){0.f, 0.f, 0.f, 0.f};
        #pragma unroll
        for (int ks = 0; ks < 8; ++ks) {
            f16x8 paH = *(const f16x8*)&pH[(st * 16 + m) * 264 + ks * 32 + quad * 8];
            f16x8 paL = *(const f16x8*)&pL[(st * 16 + m) * 264 + ks * 32 + quad * 8];
            acc2 = __builtin_amdgcn_mfma_f32_16x16x32_f16(paH, kvH[ks], acc2, 0, 0, 0);
            acc2 = __builtin_amdgcn_mfma_f32_16x16x32_f16(paH, kvL[ks], acc2, 0, 0, 0);
            acc2 = __builtin_amdgcn_mfma_f32_16x16x32_f16(paL, kvH[ks], acc2, 0, 0, 0);
        }
        #pragma unroll
        for (int r = 0; r < 4; ++r)
            oL[(st * 16 + quad * 4 + r) * 68 + dt * 16 + m] = acc2[r];
        __syncthreads();

        {
            float4 ov = *(const float4*)&oL[srow * 68 + scol * 4];
            float s = scaleL[srow];
            og[(rbase + it * 32 + srow) * 16 + scol] =
                make_float4(ov.x * s, ov.y * s, ov.z * s, ov.w * s);
        }
    }
}

extern "C" void kernel_launch(void* const* d_in, const int* in_sizes, int n_in,
                              void* d_out, int out_size, void* d_ws, size_t ws_size,
                              hipStream_t stream) {
    (void)in_sizes; (void)n_in; (void)out_size; (void)ws_size;
    const float* q = (const float*)d_in[0];
    const float* k = (const float*)d_in[1];
    const float* v = (const float*)d_in[2];
    const float* w = (const float*)d_in[3];
    float* out = (float*)d_out;
    float* ws = (float*)d_ws;

    hipMemsetAsync(d_ws, 0, WS_ZERO_BYTES, stream);
    k_stats<<<dim3(16, 64), 256, 0, stream>>>(k, ws + MSUM_OFF_F, (unsigned*)ws + NKEY_OFF_F);
    k_kv<<<dim3(8, 64), 512, 0, stream>>>(k, v, w, ws);
    k_out<<<dim3(8, 64), 512, 0, stream>>>(q, w, ws, out);
}

// Round 5
// 355.843 us; speedup vs baseline: 1.3713x; 1.0590x over previous
//
#include <hip/hip_runtime.h>

#define BB 64
#define SS 4096
#define DD 64
#define FF 256
#define INVS 0.35355339059327373f   // 1/sqrt(8) = 64^-0.25
#define FSCALE 0.0625f              // 256^-0.5

// workspace layout (float-index offsets)
#define KV_OFF_F    0                          // [BB][FF][DD]
#define KSUM_OFF_F  (BB*FF*DD)                 // [BB][FF]
#define MKEY_OFF_F  (KSUM_OFF_F + BB*FF)       // [BB] uint keys (true max k_proj)
#define NKEY_OFF_F  (MKEY_OFF_F + BB)          // [BB] uint keys (max raw row |k|^2)
#define MSUM_OFF_F  (NKEY_OFF_F + BB)          // [BB][DD] column sums of raw k
#define WS_ZERO_F   (MSUM_OFF_F + BB*DD)
#define WS_ZERO_BYTES (WS_ZERO_F * 4)

typedef _Float16 f16;
typedef __attribute__((ext_vector_type(4))) _Float16 f16x4;
typedef __attribute__((ext_vector_type(8))) _Float16 f16x8;
typedef __attribute__((ext_vector_type(4))) float f32x4;

__device__ __forceinline__ unsigned fkey(float f) {
    unsigned b = __float_as_uint(f);
    return (f < 0.0f) ? ~b : (b | 0x80000000u);
}
__device__ __forceinline__ float funkey(unsigned k) {
    return (k & 0x80000000u) ? __uint_as_float(k ^ 0x80000000u) : __uint_as_float(~k);
}
__device__ __forceinline__ void splitf(float x, f16& h, f16& l) {
    h = (f16)x;
    l = (f16)(x - (float)h);
}

// ---------------------------------------------------------------------------
// K1: per-b column sums of raw k (mean) + max raw row-norm^2. (unchanged)
// ---------------------------------------------------------------------------
__global__ __launch_bounds__(256) void k_stats(const float* __restrict__ kin,
                                               float* __restrict__ msum,
                                               unsigned* __restrict__ nkey) {
    const int b = blockIdx.y, chunk = blockIdx.x;
    const int t = threadIdx.x, row = t >> 4, c16 = t & 15;
    const float4* kg = (const float4*)(kin + (size_t)b * (SS * DD));
    float4 cacc = make_float4(0.f, 0.f, 0.f, 0.f);
    float nmax = 0.f;
    const int s0 = chunk * 256;
    #pragma unroll 4
    for (int it = 0; it < 16; ++it) {
        const int s = s0 + it * 16 + row;
        float4 x = kg[s * 16 + c16];
        cacc.x += x.x; cacc.y += x.y; cacc.z += x.z; cacc.w += x.w;
        float sq = x.x * x.x + x.y * x.y + x.z * x.z + x.w * x.w;
        #pragma unroll
        for (int off = 1; off <= 8; off <<= 1) sq += __shfl_xor(sq, off);
        nmax = fmaxf(nmax, sq);
    }
    __shared__ float csum[64];
    __shared__ float wm[4];
    if (t < 64) csum[t] = 0.f;
    __syncthreads();
    atomicAdd(&csum[c16 * 4 + 0], cacc.x);
    atomicAdd(&csum[c16 * 4 + 1], cacc.y);
    atomicAdd(&csum[c16 * 4 + 2], cacc.z);
    atomicAdd(&csum[c16 * 4 + 3], cacc.w);
    nmax = fmaxf(nmax, __shfl_xor(nmax, 16));
    nmax = fmaxf(nmax, __shfl_xor(nmax, 32));
    if ((t & 63) == 0) wm[t >> 6] = nmax;
    __syncthreads();
    if (t < 64) atomicAdd(&msum[b * DD + t], csum[t]);
    if (t == 0) {
        float mx = fmaxf(fmaxf(wm[0], wm[1]), fmaxf(wm[2], wm[3]));
        atomicMax(&nkey[b], fkey(mx));
    }
}

// ---------------------------------------------------------------------------
// K2 (MFMA): phi_k^T V.
// Round-5: barrier/latency restructure (occupancy lever abandoned — R3/R4
// showed unified VGPR+AGPR total stays >128 regardless of arch-VGPR diet).
// (a) k4/v4 prefetch issued right after bar1: phase A (~1200 cyc) covers the
//     ~900-cyc HBM latency, so bar2's implicit vmcnt(0) drain is cheap.
//     (Previously issued before bar3 with only phase B to cover -> hard
//     stall every iter at the barrier's full drain.)
// (b) bar3 removed: vT B-fragments loaded in the phase-A region, so phase B
//     reads ONLY pT; stage(i+1) (kH/vT/cS writes) conflicts with nothing
//     phase B reads, and bar1(i+1) orders pT reads vs next pT writes.
// 2 barriers/iter. Keeps swizzle + register ksum. grid (8,64).
// ---------------------------------------------------------------------------
__global__ __launch_bounds__(512, 1) void k_kv(const float* __restrict__ kin,
                                               const float* __restrict__ vin,
                                               const float* __restrict__ w,
                                               float* __restrict__ ws) {
    float* kv = ws + KV_OFF_F;
    float* ksum = ws + KSUM_OFF_F;
    unsigned* mkey = (unsigned*)ws + MKEY_OFF_F;
    const unsigned* nkey = (const unsigned*)ws + NKEY_OFF_F;
    const float* msum = ws + MSUM_OFF_F;

    const int b = blockIdx.y, chunk = blockIdx.x;
    const int t = threadIdx.x;
    const int wid = t >> 6, l = t & 63, quad = l >> 4, m = l & 15;

    __shared__ __align__(16) f16 kH[32 * 72], kL[32 * 72];
    __shared__ __align__(16) f16 vTH[64 * 40], vTL[64 * 40];
    __shared__ __align__(16) f16 pTH[256 * 40], pTL[256 * 40];
    __shared__ __align__(16) float cS[32];
    __shared__ __align__(16) float muL[64];
    __shared__ float redw[8];
    __shared__ float mhatL;

    if (t < 64) {
        float mv = msum[b * DD + t] * (1.0f / 4096.0f);
        muL[t] = mv;
        float sq = mv * mv;
        #pragma unroll
        for (int off = 32; off; off >>= 1) sq += __shfl_xor(sq, off);
        if (t == 0) mhatL = (sqrtf(funkey(nkey[b])) + sqrtf(sq)) * INVS;
    }

    // W fragments: wave wid owns f-tiles {2*wid, 2*wid+1}.
    f16x8 wbH[2][2], wbL[2][2];
    #pragma unroll
    for (int ff = 0; ff < 2; ++ff) {
        #pragma unroll
        for (int ks = 0; ks < 2; ++ks) {
            const float* wp = w + (((wid * 2 + ff) * 16 + m) * 64 + ks * 32 + quad * 8);
            float4 x0 = *(const float4*)wp;
            float4 x1 = *(const float4*)(wp + 4);
            f16 h, lo;
            splitf(x0.x, h, lo); wbH[ff][ks][0] = h; wbL[ff][ks][0] = lo;
            splitf(x0.y, h, lo); wbH[ff][ks][1] = h; wbL[ff][ks][1] = lo;
            splitf(x0.z, h, lo); wbH[ff][ks][2] = h; wbL[ff][ks][2] = lo;
            splitf(x0.w, h, lo); wbH[ff][ks][3] = h; wbL[ff][ks][3] = lo;
            splitf(x1.x, h, lo); wbH[ff][ks][4] = h; wbL[ff][ks][4] = lo;
            splitf(x1.y, h, lo); wbH[ff][ks][5] = h; wbL[ff][ks][5] = lo;
            splitf(x1.z, h, lo); wbH[ff][ks][6] = h; wbL[ff][ks][6] = lo;
            splitf(x1.w, h, lo); wbH[ff][ks][7] = h; wbL[ff][ks][7] = lo;
        }
    }
    __syncthreads();
    const float mhat = mhatL;
    const int srow = t >> 4, scol = t & 15;
    const float4 mu4 = *(const float4*)&muL[scol * 4];

    f32x4 acc2[8];
    #pragma unroll
    for (int i = 0; i < 8; ++i) acc2[i] = (f32x4){0.f, 0.f, 0.f, 0.f};
    float ksacc[2] = {0.f, 0.f};
    float dmax = -1e30f;

    const int rbase = chunk * 512;
    const float4* kg = (const float4*)(kin + (size_t)b * (SS * DD));
    const float4* vg = (const float4*)(vin + (size_t)b * (SS * DD));

    float4 k4 = kg[(rbase + srow) * 16 + scol];
    float4 v4 = vg[(rbase + srow) * 16 + scol];

    // staging-side swizzle constants
    const int vgW = scol & 3;            // (d>>2)&3 for d = scol*4+u
    const int sG = srow >> 3, sIn = srow & 7;
    const int mG = (m >> 2) & 3;         // (f>>2)&3 and (d>>2)&3 for lane m

    for (int it = 0; it < 16; ++it) {
        // ---- stage current regs -> LDS ----
        float4 kc;
        kc.x = (k4.x - mu4.x) * INVS; kc.y = (k4.y - mu4.y) * INVS;
        kc.z = (k4.z - mu4.z) * INVS; kc.w = (k4.w - mu4.w) * INVS;
        float sq = kc.x * kc.x + kc.y * kc.y + kc.z * kc.z + kc.w * kc.w;
        #pragma unroll
        for (int off = 1; off <= 8; off <<= 1) sq += __shfl_xor(sq, off);
        if (scol == 0) cS[srow] = 0.5f * sq;
        {
            f16x4 khv, klv;
            f16 h, lo;
            splitf(kc.x, h, lo); khv[0] = h; klv[0] = lo;
            splitf(kc.y, h, lo); khv[1] = h; klv[1] = lo;
            splitf(kc.z, h, lo); khv[2] = h; klv[2] = lo;
            splitf(kc.w, h, lo); khv[3] = h; klv[3] = lo;
            *(f16x4*)&kH[srow * 72 + scol * 4] = khv;
            *(f16x4*)&kL[srow * 72 + scol * 4] = klv;
        }
        #pragma unroll
        for (int u = 0; u < 4; ++u) {
            float vv = (&v4.x)[u];
            f16 vh, vl;
            splitf(vv, vh, vl);
            const int idx = (scol * 4 + u) * 40 + ((sG ^ vgW) << 3) + sIn;
            vTH[idx] = vh;
            vTL[idx] = vl;
        }
        __syncthreads();                 // bar1

        // prefetch next stage EARLY: phase A covers the HBM latency, so the
        // implicit vmcnt(0) drain at bar2 is nearly free.
        if (it < 15) {
            k4 = kg[(rbase + (it + 1) * 32 + srow) * 16 + scol];
            v4 = vg[(rbase + (it + 1) * 32 + srow) * 16 + scol];
        }

        // phase-B B-operand (vT) loads moved into the phase-A region so that
        // phase B touches only pT (enables bar3 removal).
        f16x8 bH2[4], bL2[4];
        #pragma unroll
        for (int dtile = 0; dtile < 4; ++dtile) {
            const int d = dtile * 16 + m;
            const int off = d * 40 + ((quad ^ mG) << 3);
            bH2[dtile] = *(const f16x8*)&vTH[off];
            bL2[dtile] = *(const f16x8*)&vTL[off];
        }

        // ---- phase A: both s-tiles, 2 f-tiles per wave ----
        #pragma unroll
        for (int st = 0; st < 2; ++st) {
            f16x8 aH[2], aL[2];
            #pragma unroll
            for (int ks = 0; ks < 2; ++ks) {
                aH[ks] = *(const f16x8*)&kH[(st * 16 + m) * 72 + ks * 32 + quad * 8];
                aL[ks] = *(const f16x8*)&kL[(st * 16 + m) * 72 + ks * 32 + quad * 8];
            }
            const float4 c4 = *(const float4*)&cS[st * 16 + quad * 4];
            const int pG = ((st * 2 + (quad >> 1)) ^ mG);    // swizzled s-granule
            const int pOff = (pG << 3) + ((quad & 1) << 2);
            #pragma unroll
            for (int ff = 0; ff < 2; ++ff) {
                f32x4 acc = (f32x4){0.f, 0.f, 0.f, 0.f};
                #pragma unroll
                for (int ks = 0; ks < 2; ++ks) {
                    acc = __builtin_amdgcn_mfma_f32_16x16x32_f16(aH[ks], wbH[ff][ks], acc, 0, 0, 0);
                    acc = __builtin_amdgcn_mfma_f32_16x16x32_f16(aH[ks], wbL[ff][ks], acc, 0, 0, 0);
                    acc = __builtin_amdgcn_mfma_f32_16x16x32_f16(aL[ks], wbH[ff][ks], acc, 0, 0, 0);
                }
                float ksp = 0.f;
                f16x4 phv, plv;
                #pragma unroll
                for (int r = 0; r < 4; ++r) {
                    float d = acc[r];
                    dmax = fmaxf(dmax, d);
                    float p = __expf(d - (&c4.x)[r] - mhat) * FSCALE;
                    ksp += p;
                    f16 h, lo;
                    splitf(p, h, lo);
                    phv[r] = h; plv[r] = lo;
                }
                const int f = (wid * 2 + ff) * 16 + m;
                *(f16x4*)&pTH[f * 40 + pOff] = phv;
                *(f16x4*)&pTL[f * 40 + pOff] = plv;
                ksp += __shfl_xor(ksp, 16);
                ksp += __shfl_xor(ksp, 32);
                ksacc[ff] += ksp;
            }
        }
        __syncthreads();                 // bar2

        // ---- phase B: reads ONLY pT; no trailing barrier needed ----
        f16x8 aH2[2], aL2[2];
        #pragma unroll
        for (int tt = 0; tt < 2; ++tt) {
            const int f = (wid * 2 + tt) * 16 + m;
            const int off = f * 40 + ((quad ^ mG) << 3);
            aH2[tt] = *(const f16x8*)&pTH[off];
            aL2[tt] = *(const f16x8*)&pTL[off];
        }
        #pragma unroll
        for (int tt = 0; tt < 2; ++tt) {
            #pragma unroll
            for (int dtile = 0; dtile < 4; ++dtile) {
                f32x4 a = acc2[tt * 4 + dtile];
                a = __builtin_amdgcn_mfma_f32_16x16x32_f16(aH2[tt], bH2[dtile], a, 0, 0, 0);
                a = __builtin_amdgcn_mfma_f32_16x16x32_f16(aH2[tt], bL2[dtile], a, 0, 0, 0);
                a = __builtin_amdgcn_mfma_f32_16x16x32_f16(aL2[tt], bH2[dtile], a, 0, 0, 0);
                acc2[tt * 4 + dtile] = a;
            }
        }
        // no bar3: stage(i+1) writes kH/vT/cS which phase B does not read;
        // bar1(i+1) orders phase-B pT reads against phase-A(i+1) pT writes.
    }

    // ---- epilogue ----
    #pragma unroll
    for (int tt = 0; tt < 2; ++tt) {
        #pragma unroll
        for (int dtile = 0; dtile < 4; ++dtile) {
            #pragma unroll
            for (int r = 0; r < 4; ++r) {
                const int f = (wid * 2 + tt) * 16 + quad * 4 + r;
                const int d = dtile * 16 + m;
                atomicAdd(&kv[((size_t)b * FF + f) * DD + d], acc2[tt * 4 + dtile][r]);
            }
        }
    }
    if (l < 16) {
        #pragma unroll
        for (int ff = 0; ff < 2; ++ff)
            atomicAdd(&ksum[b * FF + (wid * 2 + ff) * 16 + l], ksacc[ff]);
    }
    #pragma unroll
    for (int off = 32; off; off >>= 1) dmax = fmaxf(dmax, __shfl_xor(dmax, off));
    if (l == 0) redw[wid] = dmax;
    __syncthreads();
    if (t == 0) {
        float mx = redw[0];
        #pragma unroll
        for (int i = 1; i < 8; ++i) mx = fmaxf(mx, redw[i]);
        atomicMax(&mkey[b], fkey(mx));
    }
}

// ---------------------------------------------------------------------------
// K3 (MFMA): out = phi_q . kv / deno.
// Round-5 change: q4 prefetch moved from after-bar2 to right after bar1 so
// phase A (~24 MFMA + exps) covers the HBM latency instead of phase B.
// ---------------------------------------------------------------------------
__global__ __launch_bounds__(512, 2) void k_out(const float* __restrict__ qin,
                                                const float* __restrict__ w,
                                                const float* __restrict__ ws,
                                                float* __restrict__ outp) {
    const float* kv = ws + KV_OFF_F;
    const float* ksum = ws + KSUM_OFF_F;
    const unsigned* mkey = (const unsigned*)ws + MKEY_OFF_F;
    const unsigned* nkey = (const unsigned*)ws + NKEY_OFF_F;
    const float* msum = ws + MSUM_OFF_F;

    const int b = blockIdx.y, chunk = blockIdx.x, t = threadIdx.x;
    const int wid = t >> 6, l = t & 63, quad = l >> 4, m = l & 15;
    const int st = wid & 1, fgroup = wid >> 1;   // phase A: (s-tile, f-group)
    const int dt = wid >> 1;                     // phase B: (s-tile=st, d-tile)

    __shared__ __align__(16) f16 qH[32 * 72], qL[32 * 72];
    __shared__ __align__(16) f16 pH[32 * 264], pL[32 * 264];
    __shared__ __align__(16) float oL[32 * 68];
    __shared__ float cS[32], mqL[32];
    __shared__ float ksL[256];
    __shared__ float denoP[4][32], dmaxP[4][32];
    __shared__ float scaleL[32];
    __shared__ float abL;

    if (t < 64) {
        float mv = msum[b * DD + t] * (1.0f / 4096.0f);
        float sq = mv * mv;
        #pragma unroll
        for (int off = 32; off; off >>= 1) sq += __shfl_xor(sq, off);
        if (t == 0) {
            float mhat = (sqrtf(funkey(nkey[b])) + sqrtf(sq)) * INVS;  // same ops as k_kv
            abL = __expf(mhat - funkey(mkey[b]));                      // alpha_b >= 1
        }
    }
    if (t < 256) ksL[t] = ksum[b * FF + t];

    f16x8 wbH[4][2], wbL[4][2];
    #pragma unroll
    for (int ff = 0; ff < 4; ++ff) {
        #pragma unroll
        for (int ks = 0; ks < 2; ++ks) {
            const float* wp = w + (((fgroup * 4 + ff) * 16 + m) * 64 + ks * 32 + quad * 8);
            float4 x0 = *(const float4*)wp;
            float4 x1 = *(const float4*)(wp + 4);
            f16 h, lo;
            splitf(x0.x, h, lo); wbH[ff][ks][0] = h; wbL[ff][ks][0] = lo;
            splitf(x0.y, h, lo); wbH[ff][ks][1] = h; wbL[ff][ks][1] = lo;
            splitf(x0.z, h, lo); wbH[ff][ks][2] = h; wbL[ff][ks][2] = lo;
            splitf(x0.w, h, lo); wbH[ff][ks][3] = h; wbL[ff][ks][3] = lo;
            splitf(x1.x, h, lo); wbH[ff][ks][4] = h; wbL[ff][ks][4] = lo;
            splitf(x1.y, h, lo); wbH[ff][ks][5] = h; wbL[ff][ks][5] = lo;
            splitf(x1.z, h, lo); wbH[ff][ks][6] = h; wbL[ff][ks][6] = lo;
            splitf(x1.w, h, lo); wbH[ff][ks][7] = h; wbL[ff][ks][7] = lo;
        }
    }

    f16x8 kvH[8], kvL[8];
    {
        const float* kvg = kv + (size_t)b * (FF * DD) + dt * 16 + m;
        #pragma unroll
        for (int ks = 0; ks < 8; ++ks) {
            #pragma unroll
            for (int j = 0; j < 8; ++j) {
                float x = kvg[(ks * 32 + quad * 8 + j) * 64];
                f16 h, lo;
                splitf(x, h, lo);
                kvH[ks][j] = h; kvL[ks][j] = lo;
            }
        }
    }
    __syncthreads();

    const int srow = t >> 4, scol = t & 15;
    const int rbase = chunk * 512;
    const float4* qg = (const float4*)qin + (size_t)b * (SS * 16);
    float4* og = (float4*)outp + (size_t)b * (SS * 16);

    float4 q4 = qg[(rbase + srow) * 16 + scol];

    for (int it = 0; it < 16; ++it) {
        float4 qs;
        qs.x = q4.x * INVS; qs.y = q4.y * INVS;
        qs.z = q4.z * INVS; qs.w = q4.w * INVS;
        float sq = qs.x * qs.x + qs.y * qs.y + qs.z * qs.z + qs.w * qs.w;
        #pragma unroll
        for (int off = 1; off <= 8; off <<= 1) sq += __shfl_xor(sq, off);
        if (scol == 0) { cS[srow] = 0.5f * sq; mqL[srow] = sqrtf(sq); }
        {
            f16x4 hv, lv;
            f16 h, lo;
            splitf(qs.x, h, lo); hv[0] = h; lv[0] = lo;
            splitf(qs.y, h, lo); hv[1] = h; lv[1] = lo;
            splitf(qs.z, h, lo); hv[2] = h; lv[2] = lo;
            splitf(qs.w, h, lo); hv[3] = h; lv[3] = lo;
            *(f16x4*)&qH[srow * 72 + scol * 4] = hv;
            *(f16x4*)&qL[srow * 72 + scol * 4] = lv;
        }
        __syncthreads();                 // bar1

        // prefetch EARLY: phase A covers the HBM latency; bar2 drain cheap.
        if (it < 15) q4 = qg[(rbase + (it + 1) * 32 + srow) * 16 + scol];

        f16x8 bqH[2], bqL[2];
        #pragma unroll
        for (int ks = 0; ks < 2; ++ks) {
            bqH[ks] = *(const f16x8*)&qH[(st * 16 + m) * 72 + ks * 32 + quad * 8];
            bqL[ks] = *(const f16x8*)&qL[(st * 16 + m) * 72 + ks * 32 + quad * 8];
        }
        const float cs = cS[st * 16 + m];
        const float mq = mqL[st * 16 + m];
        float dpart = 0.f, dmax = -1e30f;
        #pragma unroll
        for (int ff = 0; ff < 4; ++ff) {
            f32x4 acc = (f32x4){0.f, 0.f, 0.f, 0.f};
            #pragma unroll
            for (int ks = 0; ks < 2; ++ks) {
                acc = __builtin_amdgcn_mfma_f32_16x16x32_f16(wbH[ff][ks], bqH[ks], acc, 0, 0, 0);
                acc = __builtin_amdgcn_mfma_f32_16x16x32_f16(wbH[ff][ks], bqL[ks], acc, 0, 0, 0);
                acc = __builtin_amdgcn_mfma_f32_16x16x32_f16(wbL[ff][ks], bqH[ks], acc, 0, 0, 0);
            }
            const int f0 = (fgroup * 4 + ff) * 16 + quad * 4;
            const float4 ksv = *(const float4*)&ksL[f0];
            f16x4 phv, plv;
            #pragma unroll
            for (int r = 0; r < 4; ++r) {
                float d = acc[r];
                dmax = fmaxf(dmax, d);
                float p = __expf(d - cs - mq);      // FSCALE folded into A later
                dpart = fmaf(p, (&ksv.x)[r], dpart);
                f16 h, lo;
                splitf(p, h, lo);
                phv[r] = h; plv[r] = lo;
            }
            *(f16x4*)&pH[(st * 16 + m) * 264 + f0] = phv;
            *(f16x4*)&pL[(st * 16 + m) * 264 + f0] = plv;
        }
        dpart += __shfl_xor(dpart, 16);
        dpart += __shfl_xor(dpart, 32);
        dmax = fmaxf(dmax, __shfl_xor(dmax, 16));
        dmax = fmaxf(dmax, __shfl_xor(dmax, 32));
        if (l < 16) {
            denoP[fgroup][st * 16 + l] = dpart;
            dmaxP[fgroup][st * 16 + l] = dmax;
        }
        __syncthreads();                 // bar2

        if (t < 32) {
            float dn0 = denoP[0][t] + denoP[1][t] + denoP[2][t] + denoP[3][t];
            float mt = fmaxf(fmaxf(dmaxP[0][t], dmaxP[1][t]),
                             fmaxf(dmaxP[2][t], dmaxP[3][t]));
            float A = abL * __expf(mqL[t] - mt) * FSCALE;
            float dn = fmaxf(A * dn0, 1e-4f);
            scaleL[t] = A / dn;
        }

        f32x4 acc2 = (f32x4){0.f, 0.f, 0.f, 0.f};
        #pragma unroll
        for (int ks = 0; ks < 8; ++ks) {
            f16x8 paH = *(const f16x8*)&pH[(st * 16 + m) * 264 + ks * 32 + quad * 8];
            f16x8 paL = *(const f16x8*)&pL[(st * 16 + m) * 264 + ks * 32 + quad * 8];
            acc2 = __builtin_amdgcn_mfma_f32_16x16x32_f16(paH, kvH[ks], acc2, 0, 0, 0);
            acc2 = __builtin_amdgcn_mfma_f32_16x16x32_f16(paH, kvL[ks], acc2, 0, 0, 0);
            acc2 = __builtin_amdgcn_mfma_f32_16x16x32_f16(paL, kvH[ks], acc2, 0, 0, 0);
        }
        #pragma unroll
        for (int r = 0; r < 4; ++r)
            oL[(st * 16 + quad * 4 + r) * 68 + dt * 16 + m] = acc2[r];
        __syncthreads();                 // bar3 (oL exchange)

        {
            float4 ov = *(const float4*)&oL[srow * 68 + scol * 4];
            float s = scaleL[srow];
            og[(rbase + it * 32 + srow) * 16 + scol] =
                make_float4(ov.x * s, ov.y * s, ov.z * s, ov.w * s);
        }
    }
}

extern "C" void kernel_launch(void* const* d_in, const int* in_sizes, int n_in,
                              void* d_out, int out_size, void* d_ws, size_t ws_size,
                              hipStream_t stream) {
    (void)in_sizes; (void)n_in; (void)out_size; (void)ws_size;
    const float* q = (const float*)d_in[0];
    const float* k = (const float*)d_in[1];
    const float* v = (const float*)d_in[2];
    const float* w = (const float*)d_in[3];
    float* out = (float*)d_out;
    float* ws = (float*)d_ws;

    hipMemsetAsync(d_ws, 0, WS_ZERO_BYTES, stream);
    k_stats<<<dim3(16, 64), 256, 0, stream>>>(k, ws + MSUM_OFF_F, (unsigned*)ws + NKEY_OFF_F);
    k_kv<<<dim3(8, 64), 512, 0, stream>>>(k, v, w, ws);
    k_out<<<dim3(8, 64), 512, 0, stream>>>(q, w, ws, out);
}